// Round 1
// baseline (2592.866 us; speedup 1.0000x reference)
//
#include <hip/hip_runtime.h>

constexpr int NB   = 1024;  // batch
constexpr int NDIM = 32;    // x dim
constexpr int NH   = 1024;  // hidden dim
constexpr int NC   = 512;   // context dim

constexpr float INV_SQRT2PI = 0.3989422804014327f;   // 1/sqrt(2*pi) == 1/(2*sqrt(pi/2))
constexpr float SQRT_HALF   = 0.70710678118654752f;  // 1/sqrt(2)
constexpr float SQRT_HPI    = 1.2533141373155003f;   // sqrt(pi/2)

__device__ __forceinline__ float sp_f(float x) {
  return (x > 20.f) ? x : log1pf(expf(x));
}

// ---------------- prep: softplus of Wz1/Wz2/Wzout (+ transposes) ----------------
__global__ __launch_bounds__(256) void k_prep(
    const float* __restrict__ Wz1, const float* __restrict__ Wz2,
    const float* __restrict__ Wzout,
    float* __restrict__ S1, float* __restrict__ S1T,
    float* __restrict__ S2, float* __restrict__ S2T,
    float* __restrict__ so)
{
  const int idx = blockIdx.x * 256 + threadIdx.x;   // 0 .. NH*NH-1
  const int i = idx >> 10, p = idx & 1023;
  const float v1 = sp_f(Wz1[idx]);
  S1[idx] = v1; S1T[p * NH + i] = v1;
  const float v2 = sp_f(Wz2[idx]);
  S2[idx] = v2; S2T[p * NH + i] = v2;
  if (idx < NH) so[idx] = sp_f(Wzout[idx]);
}

// ---------------- tiled fp32 GEMM:  C[M,1024] = A[M,K] @ Bt[1024,K]^T ----------------
// AMODE 0: A plain row-major (lda)
// AMODE 1: A[r,p] = gvec[(b0+r/32)*NH + p] * aux[p*NDIM + (r%32)]      (G0 x Wz0)
// AMODE 2: A[r,k] = gvec[(b0+r/32)*NH + k] * A[r*lda + k]              (G1 x Jh1)
// EPI 0: C = acc*scale       EPI 1: C += acc*scale
// EPI 2: C = acc*scale + wepi[n*NDIM + (r%32)]                          (adds Wx term)
template<int AMODE, int EPI>
__global__ __launch_bounds__(256) void k_gemm(
    const float* __restrict__ A, const float* __restrict__ Bt,
    float* __restrict__ C, int K, int lda, float scale,
    const float* __restrict__ gvec, const float* __restrict__ aux,
    const float* __restrict__ wepi, int b0)
{
  __shared__ float As[16][68];
  __shared__ float Bs[16][68];
  const int tid  = threadIdx.y * 16 + threadIdx.x;
  const int arow = tid >> 2;          // 0..63
  const int acol = (tid & 3) << 2;    // 0,4,8,12
  const int m0 = blockIdx.y << 6;
  const int n0 = blockIdx.x << 6;

  float acc[4][4];
#pragma unroll
  for (int i = 0; i < 4; ++i)
#pragma unroll
    for (int j = 0; j < 4; ++j) acc[i][j] = 0.f;

  const int R = m0 + arow;

  for (int k0 = 0; k0 < K; k0 += 16) {
    float4 av;
    if constexpr (AMODE == 0) {
      av = *reinterpret_cast<const float4*>(&A[(size_t)R * lda + k0 + acol]);
    } else if constexpr (AMODE == 1) {
      const int b = b0 + (R >> 5), j = R & 31;
      const float4 g = *reinterpret_cast<const float4*>(&gvec[(size_t)b * NH + k0 + acol]);
      const int kk0 = k0 + acol;
      av.x = g.x * aux[(kk0 + 0) * NDIM + j];
      av.y = g.y * aux[(kk0 + 1) * NDIM + j];
      av.z = g.z * aux[(kk0 + 2) * NDIM + j];
      av.w = g.w * aux[(kk0 + 3) * NDIM + j];
    } else {
      const int b = b0 + (R >> 5);
      const float4 g = *reinterpret_cast<const float4*>(&gvec[(size_t)b * NH + k0 + acol]);
      const float4 m = *reinterpret_cast<const float4*>(&A[(size_t)R * lda + k0 + acol]);
      av.x = g.x * m.x; av.y = g.y * m.y; av.z = g.z * m.z; av.w = g.w * m.w;
    }
    As[acol + 0][arow] = av.x; As[acol + 1][arow] = av.y;
    As[acol + 2][arow] = av.z; As[acol + 3][arow] = av.w;

    const float4 bv = *reinterpret_cast<const float4*>(&Bt[(size_t)(n0 + arow) * K + k0 + acol]);
    Bs[acol + 0][arow] = bv.x; Bs[acol + 1][arow] = bv.y;
    Bs[acol + 2][arow] = bv.z; Bs[acol + 3][arow] = bv.w;
    __syncthreads();

#pragma unroll
    for (int kk = 0; kk < 16; ++kk) {
      const float4 a  = *reinterpret_cast<const float4*>(&As[kk][threadIdx.y << 2]);
      const float4 bb = *reinterpret_cast<const float4*>(&Bs[kk][threadIdx.x << 2]);
      const float am[4] = {a.x, a.y, a.z, a.w};
      const float bn[4] = {bb.x, bb.y, bb.z, bb.w};
#pragma unroll
      for (int i2 = 0; i2 < 4; ++i2)
#pragma unroll
        for (int j2 = 0; j2 < 4; ++j2)
          acc[i2][j2] = fmaf(am[i2], bn[j2], acc[i2][j2]);
    }
    __syncthreads();
  }

#pragma unroll
  for (int i2 = 0; i2 < 4; ++i2) {
    const int row = m0 + (threadIdx.y << 2) + i2;
    const int col = n0 + (threadIdx.x << 2);
    float* cp = &C[(size_t)row * NH + col];
    float4 o;
    o.x = acc[i2][0] * scale; o.y = acc[i2][1] * scale;
    o.z = acc[i2][2] * scale; o.w = acc[i2][3] * scale;
    if constexpr (EPI == 1) {
      const float4 cur = *reinterpret_cast<const float4*>(cp);
      o.x += cur.x; o.y += cur.y; o.z += cur.z; o.w += cur.w;
    } else if constexpr (EPI == 2) {
      const int j = row & 31;
      o.x += wepi[(col + 0) * NDIM + j];
      o.y += wepi[(col + 1) * NDIM + j];
      o.z += wepi[(col + 2) * NDIM + j];
      o.w += wepi[(col + 3) * NDIM + j];
    }
    *reinterpret_cast<float4*>(cp) = o;
  }
}

// ---------------- activation (layers 0/1): writes Z, G, U ----------------
__global__ __launch_bounds__(256) void k_act(
    const float* __restrict__ HP,
    const float* __restrict__ bA, const float* __restrict__ bB,
    const float* __restrict__ bC,
    const float* __restrict__ anb, const float* __restrict__ anl,
    float* __restrict__ Z, float* __restrict__ G, float* __restrict__ U,
    int hasC)
{
  const int idx = blockIdx.x * 256 + threadIdx.x;
  const int i = idx & 1023;
  float bias = bA[i] + bB[i] + anb[i];
  if (hasC) bias += bC[i];
  const float el = expf(anl[i]);
  const float a = (HP[idx] + bias) * el;
  const float pdf = expf(-0.5f * a * a);
  const float er = erff(a * SQRT_HALF);
  Z[idx] = (SQRT_HPI * a * er + pdf + SQRT_HPI * a) * INV_SQRT2PI;  // gsp(a)
  G[idx] = 0.5f * (1.f + er) * el;                                  // gsp'(a)*el
  U[idx] = pdf * INV_SQRT2PI * el * el;                             // gsp''(a)*el^2
}

// ---------------- activation (layer 2): writes D2g = t2*g2, D2u = t2*u2 ----------------
__global__ __launch_bounds__(256) void k_act2(
    const float* __restrict__ HP,
    const float* __restrict__ bA, const float* __restrict__ bB,
    const float* __restrict__ bC,
    const float* __restrict__ anb, const float* __restrict__ anl,
    const float* __restrict__ so,
    float* __restrict__ D2g, float* __restrict__ D2u)
{
  const int idx = blockIdx.x * 256 + threadIdx.x;
  const int i = idx & 1023;
  const float bias = bA[i] + bB[i] + bC[i] + anb[i];
  const float el = expf(anl[i]);
  const float a = (HP[idx] + bias) * el;
  const float pdf = expf(-0.5f * a * a);
  const float er = erff(a * SQRT_HALF);
  const float g = 0.5f * (1.f + er) * el;
  const float u = pdf * INV_SQRT2PI * el * el;
  const float t2 = so[i] * (1.f / NH);
  D2g[idx] = t2 * g;
  D2u[idx] = t2 * u;
}

__global__ __launch_bounds__(256) void k_bw1(
    const float* __restrict__ T1, const float* __restrict__ G1,
    const float* __restrict__ U1,
    float* __restrict__ E1, float* __restrict__ D1)
{
  const int idx = blockIdx.x * 256 + threadIdx.x;
  const float t = T1[idx];
  E1[idx] = t * G1[idx];
  D1[idx] = t * U1[idx];
}

__global__ __launch_bounds__(256) void k_bw0(
    const float* __restrict__ T0, const float* __restrict__ U0,
    float* __restrict__ D0)
{
  const int idx = blockIdx.x * 256 + threadIdx.x;
  D0[idx] = T0[idx] * U0[idx];
}

// ---------------- per-sample Gram assembly + f + Cholesky logdet ----------------
__global__ __launch_bounds__(256) void k_assemble(
    const float* __restrict__ M1buf, const float* __restrict__ M2buf, // [CB*32, NH]
    const float* __restrict__ D0, const float* __restrict__ D1,
    const float* __restrict__ D2u, const float* __restrict__ D2g,
    const float* __restrict__ Wz0, const float* __restrict__ X,
    const float* __restrict__ Wxout,
    const float* __restrict__ w0p, const float* __restrict__ w1p,
    float* __restrict__ outF, float* __restrict__ outLD, int b0)
{
  const int bl = blockIdx.x;
  const int b = b0 + bl;
  const int tid = threadIdx.x;

  __shared__ float sM[64][36];
  __shared__ float sD[64];
  __shared__ float sDg[64];
  __shared__ float pH[4][1024];
  __shared__ float vpart[4][32];
  __shared__ float sH[32][33];
  __shared__ float sred[32];

  const int q = tid >> 6;           // wave id 0..3 (i-split)
  const int o = tid & 63;
  const int j0 = (o >> 3) << 2;     // 0,4,...,28
  const int k0 = (o & 7) << 2;      // 0,4,...,28

  float acc[4][4];
#pragma unroll
  for (int i = 0; i < 4; ++i)
#pragma unroll
    for (int j = 0; j < 4; ++j) acc[i][j] = 0.f;
  float vacc = 0.f;

  for (int layer = 0; layer < 3; ++layer) {
    const float* dsrc = (layer == 0) ? D0 : (layer == 1) ? D1 : D2u;
    const float* Mbuf = (layer == 1) ? M1buf : M2buf;
    for (int i0 = 0; i0 < NH; i0 += 64) {
      if (layer == 0) {
        for (int t = tid; t < 512; t += 256) {
          const int row = t >> 3, c4 = (t & 7) << 2;
          const float4 v = *reinterpret_cast<const float4*>(&Wz0[(i0 + row) * NDIM + c4]);
          *reinterpret_cast<float4*>(&sM[row][c4]) = v;
        }
      } else {
        for (int t = tid; t < 512; t += 256) {
          const int j = t >> 4, i4 = (t & 15) << 2;
          const float4 v = *reinterpret_cast<const float4*>(
              &Mbuf[(size_t)(bl * 32 + j) * NH + i0 + i4]);
          sM[i4 + 0][j] = v.x; sM[i4 + 1][j] = v.y;
          sM[i4 + 2][j] = v.z; sM[i4 + 3][j] = v.w;
        }
      }
      if (tid < 64) sD[tid] = dsrc[(size_t)b * NH + i0 + tid];
      if (layer == 2 && tid >= 64 && tid < 128) sDg[tid - 64] = D2g[(size_t)b * NH + i0 + (tid - 64)];
      __syncthreads();

#pragma unroll 4
      for (int t = 0; t < 16; ++t) {
        const int ii = (q << 4) + t;
        const float dv = sD[ii];
        const float4 aj = *reinterpret_cast<const float4*>(&sM[ii][j0]);
        const float4 ak = *reinterpret_cast<const float4*>(&sM[ii][k0]);
        const float dj[4] = {dv * aj.x, dv * aj.y, dv * aj.z, dv * aj.w};
        const float av[4] = {ak.x, ak.y, ak.z, ak.w};
#pragma unroll
        for (int jj = 0; jj < 4; ++jj)
#pragma unroll
          for (int kk = 0; kk < 4; ++kk)
            acc[jj][kk] = fmaf(dj[jj], av[kk], acc[jj][kk]);
        if (layer == 2 && o < 32) vacc = fmaf(sDg[ii], sM[ii][o], vacc);
      }
      __syncthreads();
    }
  }

#pragma unroll
  for (int jj = 0; jj < 4; ++jj)
#pragma unroll
    for (int kk = 0; kk < 4; ++kk)
      pH[q][(j0 + jj) * 32 + (k0 + kk)] = acc[jj][kk];
  if (o < 32) vpart[q][o] = vacc;
  __syncthreads();

  const float spw0 = sp_f(w0p[0]);
  const float spw1 = sp_f(w1p[0]);

  for (int e = tid; e < 1024; e += 256) {
    float h = pH[0][e] + pH[1][e] + pH[2][e] + pH[3][e];
    const int j = e >> 5, k = e & 31;
    h *= spw1;
    if (j == k) h += spw0;
    sH[j][k] = h;
  }
  if (tid < 32) {
    const float v = vpart[0][tid] + vpart[1][tid] + vpart[2][tid] + vpart[3][tid];
    outF[(size_t)b * NDIM + tid] = spw1 * (v + Wxout[tid]) + spw0 * X[(size_t)b * NDIM + tid];
  }
  __syncthreads();

  // in-place Cholesky on SPD sH; logdet = sum log(s_c)
  float ldacc = 0.f;
  for (int c = 0; c < 32; ++c) {
    if (tid >= c && tid < 32) {
      float s = sH[tid][c];
      for (int m = 0; m < c; ++m) s -= sH[tid][m] * sH[c][m];
      sred[tid] = s;
    }
    __syncthreads();
    const float sc = sred[c];
    if (tid >= c && tid < 32) {
      const float lcc = sqrtf(sc);
      sH[tid][c] = (tid == c) ? lcc : sred[tid] / lcc;
    }
    ldacc += logf(sc);
    __syncthreads();
  }
  if (tid == 0) outLD[b] = ldacc;
}

// ---------------- launcher ----------------
extern "C" void kernel_launch(void* const* d_in, const int* in_sizes, int n_in,
                              void* d_out, int out_size, void* d_ws, size_t ws_size,
                              hipStream_t stream)
{
  const float* X    = (const float*)d_in[0];
  const float* Cc   = (const float*)d_in[1];
  const float* w0   = (const float*)d_in[2];
  const float* w1   = (const float*)d_in[3];
  const float* Wz0w = (const float*)d_in[4];
  const float* Wz0b = (const float*)d_in[5];
  const float* Wc0w = (const float*)d_in[6];
  const float* Wc0b = (const float*)d_in[7];
  const float* an0b = (const float*)d_in[8];
  const float* an0l = (const float*)d_in[9];
  const float* Wz1w = (const float*)d_in[10];
  const float* Wz1b = (const float*)d_in[11];
  const float* Wx1w = (const float*)d_in[12];
  const float* Wx1b = (const float*)d_in[13];
  const float* Wc1w = (const float*)d_in[14];
  const float* Wc1b = (const float*)d_in[15];
  const float* an1b = (const float*)d_in[16];
  const float* an1l = (const float*)d_in[17];
  const float* Wz2w = (const float*)d_in[18];
  const float* Wz2b = (const float*)d_in[19];
  const float* Wx2w = (const float*)d_in[20];
  const float* Wx2b = (const float*)d_in[21];
  const float* Wc2w = (const float*)d_in[22];
  const float* Wc2b = (const float*)d_in[23];
  const float* an2b = (const float*)d_in[24];
  const float* an2l = (const float*)d_in[25];
  const float* Wzoutw = (const float*)d_in[26];
  const float* Wxoutw = (const float*)d_in[27];
  // d_in[28] (Wcout_w): constant in x -> no contribution to grad/Hessian.

  float* ws = (float*)d_ws;
  size_t off = 0;
  auto alloc = [&](size_t n) { float* p = ws + off; off += n; return p; };
  const size_t HH = (size_t)NH * NH;   // 1M
  const size_t BH = (size_t)NB * NH;   // 1M

  float* S1  = alloc(HH);
  float* S2  = alloc(HH);
  float* S1T = alloc(HH);
  float* S2T = alloc(HH);
  float* so  = alloc(1024);
  float* HP  = alloc(BH);
  float* Z0  = alloc(BH);
  float* Z1  = alloc(BH);
  float* G0  = alloc(BH);
  float* U0  = alloc(BH);
  float* G1  = alloc(BH);
  float* U1  = alloc(BH);
  float* D2g = alloc(BH);
  float* D2u = alloc(BH);
  float* T1  = alloc(BH);
  float* E1  = alloc(BH);
  float* D1  = alloc(BH);
  float* T0  = alloc(BH);
  float* D0  = alloc(BH);

  // pick largest chunk of samples whose two Jacobian buffers fit the workspace
  const size_t avail_f = ws_size / sizeof(float);
  int CB = 32;
  const int cands[5] = {1024, 512, 256, 128, 64};
  for (int ci = 0; ci < 5; ++ci) {
    const size_t need = off + 2 * (size_t)cands[ci] * 32 * NH;
    if (need <= avail_f) { CB = cands[ci]; break; }
  }
  float* Jh1 = alloc((size_t)CB * 32 * NH);
  float* Jh2 = alloc((size_t)CB * 32 * NH);

  float* outF  = (float*)d_out;            // [NB, NDIM]
  float* outLD = (float*)d_out + NB * NDIM; // [NB]

  const dim3 blk(16, 16);
  const dim3 gridB(16, NB / 64);
  const dim3 gridE(NB * NH / 256);
  const float invH = 1.0f / (float)NH;

  k_prep<<<dim3(HH / 256), dim3(256), 0, stream>>>(Wz1w, Wz2w, Wzoutw, S1, S1T, S2, S2T, so);

  // layer 0
  k_gemm<0, 0><<<gridB, blk, 0, stream>>>(X,  Wz0w, HP, NDIM, NDIM, 1.f, nullptr, nullptr, nullptr, 0);
  k_gemm<0, 1><<<gridB, blk, 0, stream>>>(Cc, Wc0w, HP, NC,   NC,   1.f, nullptr, nullptr, nullptr, 0);
  k_act<<<gridE, dim3(256), 0, stream>>>(HP, Wz0b, Wc0b, nullptr, an0b, an0l, Z0, G0, U0, 0);
  // layer 1
  k_gemm<0, 0><<<gridB, blk, 0, stream>>>(Z0, S1,   HP, NH,   NH,   invH, nullptr, nullptr, nullptr, 0);
  k_gemm<0, 1><<<gridB, blk, 0, stream>>>(X,  Wx1w, HP, NDIM, NDIM, 1.f,  nullptr, nullptr, nullptr, 0);
  k_gemm<0, 1><<<gridB, blk, 0, stream>>>(Cc, Wc1w, HP, NC,   NC,   1.f,  nullptr, nullptr, nullptr, 0);
  k_act<<<gridE, dim3(256), 0, stream>>>(HP, Wz1b, Wx1b, Wc1b, an1b, an1l, Z1, G1, U1, 1);
  // layer 2
  k_gemm<0, 0><<<gridB, blk, 0, stream>>>(Z1, S2,   HP, NH,   NH,   invH, nullptr, nullptr, nullptr, 0);
  k_gemm<0, 1><<<gridB, blk, 0, stream>>>(X,  Wx2w, HP, NDIM, NDIM, 1.f,  nullptr, nullptr, nullptr, 0);
  k_gemm<0, 1><<<gridB, blk, 0, stream>>>(Cc, Wc2w, HP, NC,   NC,   1.f,  nullptr, nullptr, nullptr, 0);
  k_act2<<<gridE, dim3(256), 0, stream>>>(HP, Wz2b, Wx2b, Wc2b, an2b, an2l, so, D2g, D2u);
  // backward sensitivities
  k_gemm<0, 0><<<gridB, blk, 0, stream>>>(D2g, S2T, T1, NH, NH, invH, nullptr, nullptr, nullptr, 0);
  k_bw1<<<gridE, dim3(256), 0, stream>>>(T1, G1, U1, E1, D1);
  k_gemm<0, 0><<<gridB, blk, 0, stream>>>(E1, S1T, T0, NH, NH, invH, nullptr, nullptr, nullptr, 0);
  k_bw0<<<gridE, dim3(256), 0, stream>>>(T0, U0, D0);

  // Jacobian propagation + Gram assembly, chunked over samples
  const dim3 gridJ(16, CB * 32 / 64);
  for (int b0 = 0; b0 < NB; b0 += CB) {
    k_gemm<1, 2><<<gridJ, blk, 0, stream>>>(nullptr, S1, Jh1, NH, 0,  invH, G0, Wz0w, Wx1w, b0);
    k_gemm<2, 2><<<gridJ, blk, 0, stream>>>(Jh1,     S2, Jh2, NH, NH, invH, G1, nullptr, Wx2w, b0);
    k_assemble<<<dim3(CB), dim3(256), 0, stream>>>(Jh1, Jh2, D0, D1, D2u, D2g,
                                                   Wz0w, X, Wxoutw, w0, w1,
                                                   outF, outLD, b0);
  }
}

// Round 2
// 1036.685 us; speedup vs baseline: 2.5011x; 2.5011x over previous
//
#include <hip/hip_runtime.h>

constexpr int NB   = 1024;  // batch
constexpr int NDIM = 32;    // x dim
constexpr int NH   = 1024;  // hidden dim
constexpr int NC   = 512;   // context dim

constexpr float INV_SQRT2PI = 0.3989422804014327f;
constexpr float SQRT_HALF   = 0.70710678118654752f;
constexpr float SQRT_HPI    = 1.2533141373155003f;

typedef __attribute__((ext_vector_type(8))) short short8;
typedef __attribute__((ext_vector_type(4))) float float4v;

__device__ __forceinline__ float sp_f(float x) {
  return (x > 20.f) ? x : log1pf(expf(x));
}

__device__ __forceinline__ short f2bf(float f) {
  union { float f; unsigned u; } x; x.f = f;
  const unsigned r = x.u + 0x7fffu + ((x.u >> 16) & 1u);
  return (short)(r >> 16);
}

__device__ __forceinline__ void async_ld16(const void* g, void* l) {
  __builtin_amdgcn_global_load_lds(
      (const __attribute__((address_space(1))) void*)g,
      (__attribute__((address_space(3))) void*)l, 16, 0, 0);
}

// ---------------- prep: softplus(Wz1/Wz2/Wzout) -> bf16 (+ transposes) ----------------
__global__ __launch_bounds__(256) void k_prep(
    const float* __restrict__ Wz1, const float* __restrict__ Wz2,
    const float* __restrict__ Wzout,
    short* __restrict__ S1b, short* __restrict__ S1Tb,
    short* __restrict__ S2b, short* __restrict__ S2Tb,
    float* __restrict__ so)
{
  const int idx = blockIdx.x * 256 + threadIdx.x;   // 0 .. NH*NH-1
  const int i = idx >> 10, p = idx & 1023;
  const float v1 = sp_f(Wz1[idx]);
  const short b1 = f2bf(v1);
  S1b[idx] = b1; S1Tb[p * NH + i] = b1;
  const float v2 = sp_f(Wz2[idx]);
  const short b2 = f2bf(v2);
  S2b[idx] = b2; S2Tb[p * NH + i] = b2;
  if (idx < NH) so[idx] = sp_f(Wzout[idx]);
}

// ---------------- fp32 tiled GEMM (kept for K=32 / K=512 terms) ----------------
// C[M,1024] = A[M,K] @ Bt[1024,K]^T ; EPI 0: C=acc, EPI 1: C+=acc
template<int EPI>
__global__ __launch_bounds__(256) void k_gemm(
    const float* __restrict__ A, const float* __restrict__ Bt,
    float* __restrict__ C, int K, int lda, float scale)
{
  __shared__ float As[16][68];
  __shared__ float Bs[16][68];
  const int tid  = threadIdx.y * 16 + threadIdx.x;
  const int arow = tid >> 2;
  const int acol = (tid & 3) << 2;
  const int m0 = blockIdx.y << 6;
  const int n0 = blockIdx.x << 6;

  float acc[4][4];
#pragma unroll
  for (int i = 0; i < 4; ++i)
#pragma unroll
    for (int j = 0; j < 4; ++j) acc[i][j] = 0.f;

  const int R = m0 + arow;
  for (int k0 = 0; k0 < K; k0 += 16) {
    const float4 av = *reinterpret_cast<const float4*>(&A[(size_t)R * lda + k0 + acol]);
    As[acol + 0][arow] = av.x; As[acol + 1][arow] = av.y;
    As[acol + 2][arow] = av.z; As[acol + 3][arow] = av.w;
    const float4 bv = *reinterpret_cast<const float4*>(&Bt[(size_t)(n0 + arow) * K + k0 + acol]);
    Bs[acol + 0][arow] = bv.x; Bs[acol + 1][arow] = bv.y;
    Bs[acol + 2][arow] = bv.z; Bs[acol + 3][arow] = bv.w;
    __syncthreads();
#pragma unroll
    for (int kk = 0; kk < 16; ++kk) {
      const float4 a  = *reinterpret_cast<const float4*>(&As[kk][threadIdx.y << 2]);
      const float4 bb = *reinterpret_cast<const float4*>(&Bs[kk][threadIdx.x << 2]);
      const float am[4] = {a.x, a.y, a.z, a.w};
      const float bn[4] = {bb.x, bb.y, bb.z, bb.w};
#pragma unroll
      for (int i2 = 0; i2 < 4; ++i2)
#pragma unroll
        for (int j2 = 0; j2 < 4; ++j2)
          acc[i2][j2] = fmaf(am[i2], bn[j2], acc[i2][j2]);
    }
    __syncthreads();
  }
#pragma unroll
  for (int i2 = 0; i2 < 4; ++i2) {
    const int row = m0 + (threadIdx.y << 2) + i2;
    const int col = n0 + (threadIdx.x << 2);
    float* cp = &C[(size_t)row * NH + col];
    float4 o;
    o.x = acc[i2][0] * scale; o.y = acc[i2][1] * scale;
    o.z = acc[i2][2] * scale; o.w = acc[i2][3] * scale;
    if constexpr (EPI == 1) {
      const float4 cur = *reinterpret_cast<const float4*>(cp);
      o.x += cur.x; o.y += cur.y; o.z += cur.z; o.w += cur.w;
    }
    *reinterpret_cast<float4*>(cp) = o;
  }
}

// ---------------- bf16 MFMA GEMM: C[M,1024] = scale*A[M,K]@Bt[1024,K]^T ----------------
// m97 structure: 128x128 tile, 4 waves, 4x4 frags of 16x16x32, global_load_lds width 16.
// EPI 0: C = acc*scale                               (forward/backward GEMMs)
// EPI 1: C = acc*scale + wepi[n*NDIM + (r&31)]        (Jh2: + Wx2 term)
// EPI 2: as EPI1, plus C2 = bf16(C * gvec[(b0+r/32)*NH + n])   (Jh1 -> Ahat2 fused)
template<int EPI>
__global__ __launch_bounds__(256) void k_mgemm(
    const short* __restrict__ A, const short* __restrict__ Bt,
    float* __restrict__ C, short* __restrict__ C2,
    const float* __restrict__ gvec, const float* __restrict__ wepi,
    float scale, int K, int b0)
{
  __shared__ short As[128 * 32];
  __shared__ short Bs[128 * 32];
  const int tid  = threadIdx.x;
  const int wave = tid >> 6, lane = tid & 63;
  const int m0 = blockIdx.y << 7, n0 = blockIdx.x << 7;
  const int wm = (wave >> 1) << 6, wn = (wave & 1) << 6;
  const int qd = lane >> 4, md = lane & 15;

  float4v acc[4][4];
#pragma unroll
  for (int i = 0; i < 4; ++i)
#pragma unroll
    for (int j = 0; j < 4; ++j) acc[i][j] = (float4v)(0.f);

  const int sr = lane >> 2;         // row within a 16-row chunk
  const int sc = (lane & 3) << 3;   // bf16-element col offset: 0,8,16,24

  for (int k0 = 0; k0 < K; k0 += 32) {
#pragma unroll
    for (int i = 0; i < 2; ++i) {
      const int ch  = wave * 2 + i;        // 0..7, wave-uniform
      const int row = ch * 16 + sr;        // 0..127
      async_ld16(&A [(size_t)(m0 + row) * K + k0 + sc], &As[ch * 512]);
      async_ld16(&Bt[(size_t)(n0 + row) * K + k0 + sc], &Bs[ch * 512]);
    }
    __syncthreads();
    short8 af[4], bfr[4];
#pragma unroll
    for (int t = 0; t < 4; ++t) {
      af[t]  = *(const short8*)&As[(wm + t * 16 + md) * 32 + qd * 8];
      bfr[t] = *(const short8*)&Bs[(wn + t * 16 + md) * 32 + qd * 8];
    }
#pragma unroll
    for (int i = 0; i < 4; ++i)
#pragma unroll
      for (int j = 0; j < 4; ++j)
        acc[i][j] = __builtin_amdgcn_mfma_f32_16x16x32_bf16(af[i], bfr[j], acc[i][j], 0, 0, 0);
    __syncthreads();
  }

#pragma unroll
  for (int i = 0; i < 4; ++i) {
#pragma unroll
    for (int j = 0; j < 4; ++j) {
      const int colg = n0 + wn + j * 16 + md;
#pragma unroll
      for (int r = 0; r < 4; ++r) {
        const int rowg = m0 + wm + i * 16 + qd * 4 + r;
        float v = acc[i][j][r] * scale;
        if constexpr (EPI >= 1) v += wepi[colg * NDIM + (rowg & 31)];
        C[(size_t)rowg * NH + colg] = v;
        if constexpr (EPI == 2)
          C2[(size_t)rowg * NH + colg] =
              f2bf(v * gvec[(size_t)(b0 + (rowg >> 5)) * NH + colg]);
      }
    }
  }
}

// ---------------- activation (layers 0/1): writes Zbf (bf16), G, U ----------------
__global__ __launch_bounds__(256) void k_act(
    const float* __restrict__ HP,
    const float* __restrict__ bA, const float* __restrict__ bB,
    const float* __restrict__ bC,
    const float* __restrict__ anb, const float* __restrict__ anl,
    short* __restrict__ Zbf, float* __restrict__ G, float* __restrict__ U,
    int hasC)
{
  const int idx = blockIdx.x * 256 + threadIdx.x;
  const int i = idx & 1023;
  float bias = bA[i] + bB[i] + anb[i];
  if (hasC) bias += bC[i];
  const float el = expf(anl[i]);
  const float a = (HP[idx] + bias) * el;
  const float pdf = expf(-0.5f * a * a);
  const float er = erff(a * SQRT_HALF);
  Zbf[idx] = f2bf((SQRT_HPI * a * er + pdf + SQRT_HPI * a) * INV_SQRT2PI);
  G[idx] = 0.5f * (1.f + er) * el;
  U[idx] = pdf * INV_SQRT2PI * el * el;
}

// ---------------- activation (layer 2): D2g = t2*g2 (fp32+bf16), D2u = t2*u2 ----------------
__global__ __launch_bounds__(256) void k_act2(
    const float* __restrict__ HP,
    const float* __restrict__ bA, const float* __restrict__ bB,
    const float* __restrict__ bC,
    const float* __restrict__ anb, const float* __restrict__ anl,
    const float* __restrict__ so,
    float* __restrict__ D2g, float* __restrict__ D2u, short* __restrict__ D2gbf)
{
  const int idx = blockIdx.x * 256 + threadIdx.x;
  const int i = idx & 1023;
  const float bias = bA[i] + bB[i] + bC[i] + anb[i];
  const float el = expf(anl[i]);
  const float a = (HP[idx] + bias) * el;
  const float pdf = expf(-0.5f * a * a);
  const float er = erff(a * SQRT_HALF);
  const float g = 0.5f * (1.f + er) * el;
  const float u = pdf * INV_SQRT2PI * el * el;
  const float t2 = so[i] * (1.f / NH);
  const float dg = t2 * g;
  D2g[idx] = dg;
  D2u[idx] = t2 * u;
  D2gbf[idx] = f2bf(dg);
}

__global__ __launch_bounds__(256) void k_bw1(
    const float* __restrict__ T1, const float* __restrict__ G1,
    const float* __restrict__ U1,
    short* __restrict__ E1bf, float* __restrict__ D1)
{
  const int idx = blockIdx.x * 256 + threadIdx.x;
  const float t = T1[idx];
  E1bf[idx] = f2bf(t * G1[idx]);
  D1[idx] = t * U1[idx];
}

__global__ __launch_bounds__(256) void k_bw0(
    const float* __restrict__ T0, const float* __restrict__ U0,
    float* __restrict__ D0)
{
  const int idx = blockIdx.x * 256 + threadIdx.x;
  D0[idx] = T0[idx] * U0[idx];
}

// ---------------- Ahat1[r,p] = bf16( G0[b,p] * Wz0[p, r&31] ) ----------------
__global__ __launch_bounds__(256) void k_ahat1(
    const float* __restrict__ G0, const float* __restrict__ Wz0,
    short* __restrict__ Ahat1, int b0)
{
  const int idx = blockIdx.x * 256 + threadIdx.x;
  const int p = idx & 1023, r = idx >> 10;
  const int b = b0 + (r >> 5), j = r & 31;
  Ahat1[idx] = f2bf(G0[(size_t)b * NH + p] * Wz0[p * NDIM + j]);
}

// ---------------- per-sample Gram assembly + f + Cholesky logdet ----------------
__global__ __launch_bounds__(256) void k_assemble(
    const float* __restrict__ M1buf, const float* __restrict__ M2buf, // [CB*32, NH]
    const float* __restrict__ D0, const float* __restrict__ D1,
    const float* __restrict__ D2u, const float* __restrict__ D2g,
    const float* __restrict__ Wz0, const float* __restrict__ X,
    const float* __restrict__ Wxout,
    const float* __restrict__ w0p, const float* __restrict__ w1p,
    float* __restrict__ outF, float* __restrict__ outLD, int b0)
{
  const int bl = blockIdx.x;
  const int b = b0 + bl;
  const int tid = threadIdx.x;

  __shared__ float sM[64][36];
  __shared__ float sD[64];
  __shared__ float sDg[64];
  __shared__ float pH[4][1024];
  __shared__ float vpart[4][32];
  __shared__ float sH[32][33];
  __shared__ float sred[32];

  const int q = tid >> 6;
  const int o = tid & 63;
  const int j0 = (o >> 3) << 2;
  const int k0 = (o & 7) << 2;

  float acc[4][4];
#pragma unroll
  for (int i = 0; i < 4; ++i)
#pragma unroll
    for (int j = 0; j < 4; ++j) acc[i][j] = 0.f;
  float vacc = 0.f;

  for (int layer = 0; layer < 3; ++layer) {
    const float* dsrc = (layer == 0) ? D0 : (layer == 1) ? D1 : D2u;
    const float* Mbuf = (layer == 1) ? M1buf : M2buf;
    for (int i0 = 0; i0 < NH; i0 += 64) {
      if (layer == 0) {
        for (int t = tid; t < 512; t += 256) {
          const int row = t >> 3, c4 = (t & 7) << 2;
          const float4 v = *reinterpret_cast<const float4*>(&Wz0[(i0 + row) * NDIM + c4]);
          *reinterpret_cast<float4*>(&sM[row][c4]) = v;
        }
      } else {
        for (int t = tid; t < 512; t += 256) {
          const int j = t >> 4, i4 = (t & 15) << 2;
          const float4 v = *reinterpret_cast<const float4*>(
              &Mbuf[(size_t)(bl * 32 + j) * NH + i0 + i4]);
          sM[i4 + 0][j] = v.x; sM[i4 + 1][j] = v.y;
          sM[i4 + 2][j] = v.z; sM[i4 + 3][j] = v.w;
        }
      }
      if (tid < 64) sD[tid] = dsrc[(size_t)b * NH + i0 + tid];
      if (layer == 2 && tid >= 64 && tid < 128) sDg[tid - 64] = D2g[(size_t)b * NH + i0 + (tid - 64)];
      __syncthreads();

#pragma unroll 4
      for (int t = 0; t < 16; ++t) {
        const int ii = (q << 4) + t;
        const float dv = sD[ii];
        const float4 aj = *reinterpret_cast<const float4*>(&sM[ii][j0]);
        const float4 ak = *reinterpret_cast<const float4*>(&sM[ii][k0]);
        const float dj[4] = {dv * aj.x, dv * aj.y, dv * aj.z, dv * aj.w};
        const float av[4] = {ak.x, ak.y, ak.z, ak.w};
#pragma unroll
        for (int jj = 0; jj < 4; ++jj)
#pragma unroll
          for (int kk = 0; kk < 4; ++kk)
            acc[jj][kk] = fmaf(dj[jj], av[kk], acc[jj][kk]);
        if (layer == 2 && o < 32) vacc = fmaf(sDg[ii], sM[ii][o], vacc);
      }
      __syncthreads();
    }
  }

#pragma unroll
  for (int jj = 0; jj < 4; ++jj)
#pragma unroll
    for (int kk = 0; kk < 4; ++kk)
      pH[q][(j0 + jj) * 32 + (k0 + kk)] = acc[jj][kk];
  if (o < 32) vpart[q][o] = vacc;
  __syncthreads();

  const float spw0 = sp_f(w0p[0]);
  const float spw1 = sp_f(w1p[0]);

  for (int e = tid; e < 1024; e += 256) {
    float h = pH[0][e] + pH[1][e] + pH[2][e] + pH[3][e];
    const int j = e >> 5, k = e & 31;
    h *= spw1;
    if (j == k) h += spw0;
    sH[j][k] = h;
  }
  if (tid < 32) {
    const float v = vpart[0][tid] + vpart[1][tid] + vpart[2][tid] + vpart[3][tid];
    outF[(size_t)b * NDIM + tid] = spw1 * (v + Wxout[tid]) + spw0 * X[(size_t)b * NDIM + tid];
  }
  __syncthreads();

  float ldacc = 0.f;
  for (int c = 0; c < 32; ++c) {
    if (tid >= c && tid < 32) {
      float s = sH[tid][c];
      for (int m = 0; m < c; ++m) s -= sH[tid][m] * sH[c][m];
      sred[tid] = s;
    }
    __syncthreads();
    const float sc = sred[c];
    if (tid >= c && tid < 32) {
      const float lcc = sqrtf(sc);
      sH[tid][c] = (tid == c) ? lcc : sred[tid] / lcc;
    }
    ldacc += logf(sc);
    __syncthreads();
  }
  if (tid == 0) outLD[b] = ldacc;
}

// ---------------- launcher ----------------
extern "C" void kernel_launch(void* const* d_in, const int* in_sizes, int n_in,
                              void* d_out, int out_size, void* d_ws, size_t ws_size,
                              hipStream_t stream)
{
  const float* X    = (const float*)d_in[0];
  const float* Cc   = (const float*)d_in[1];
  const float* w0   = (const float*)d_in[2];
  const float* w1   = (const float*)d_in[3];
  const float* Wz0w = (const float*)d_in[4];
  const float* Wz0b = (const float*)d_in[5];
  const float* Wc0w = (const float*)d_in[6];
  const float* Wc0b = (const float*)d_in[7];
  const float* an0b = (const float*)d_in[8];
  const float* an0l = (const float*)d_in[9];
  const float* Wz1w = (const float*)d_in[10];
  const float* Wz1b = (const float*)d_in[11];
  const float* Wx1w = (const float*)d_in[12];
  const float* Wx1b = (const float*)d_in[13];
  const float* Wc1w = (const float*)d_in[14];
  const float* Wc1b = (const float*)d_in[15];
  const float* an1b = (const float*)d_in[16];
  const float* an1l = (const float*)d_in[17];
  const float* Wz2w = (const float*)d_in[18];
  const float* Wz2b = (const float*)d_in[19];
  const float* Wx2w = (const float*)d_in[20];
  const float* Wx2b = (const float*)d_in[21];
  const float* Wc2w = (const float*)d_in[22];
  const float* Wc2b = (const float*)d_in[23];
  const float* an2b = (const float*)d_in[24];
  const float* an2l = (const float*)d_in[25];
  const float* Wzoutw = (const float*)d_in[26];
  const float* Wxoutw = (const float*)d_in[27];
  // d_in[28] (Wcout_w): constant in x -> no grad/Hessian contribution.

  float* ws = (float*)d_ws;
  size_t off = 0;
  auto alloc = [&](size_t n) {                 // n in floats, 16B-aligned
    float* p = ws + off; off += (n + 3) & ~(size_t)3; return p;
  };
  const size_t HH = (size_t)NH * NH;
  const size_t BH = (size_t)NB * NH;

  short* S1b  = (short*)alloc(HH / 2);
  short* S2b  = (short*)alloc(HH / 2);
  short* S1Tb = (short*)alloc(HH / 2);
  short* S2Tb = (short*)alloc(HH / 2);
  float* so   = alloc(1024);
  float* HP   = alloc(BH);
  short* Z0b  = (short*)alloc(BH / 2);
  short* Z1b  = (short*)alloc(BH / 2);
  float* G0   = alloc(BH);
  float* U0   = alloc(BH);
  float* G1   = alloc(BH);
  float* U1   = alloc(BH);
  float* D2g  = alloc(BH);
  float* D2u  = alloc(BH);
  short* D2gb = (short*)alloc(BH / 2);
  float* T1   = alloc(BH);
  short* E1b  = (short*)alloc(BH / 2);
  float* D1   = alloc(BH);
  float* T0   = alloc(BH);
  float* D0   = alloc(BH);

  // chunk size: 2 fp32 J buffers + 2 bf16 Ahat buffers per chunk
  const size_t avail_f = ws_size / sizeof(float);
  int CB = 32;
  const int cands[5] = {1024, 512, 256, 128, 64};
  for (int ci = 0; ci < 5; ++ci) {
    const size_t need = off + (size_t)cands[ci] * (2 * 32 * NH + 32 * NH) + 64;
    if (need <= avail_f) { CB = cands[ci]; break; }
  }
  float* Jh1  = alloc((size_t)CB * 32 * NH);
  float* Jh2  = alloc((size_t)CB * 32 * NH);
  short* Ah1  = (short*)alloc((size_t)CB * 32 * NH / 2);
  short* Ah2  = (short*)alloc((size_t)CB * 32 * NH / 2);

  float* outF  = (float*)d_out;
  float* outLD = (float*)d_out + NB * NDIM;

  const dim3 blk2(16, 16);
  const dim3 gridB(16, NB / 64);          // fp32 gemm over [1024 x 1024]
  const dim3 gridE(NB * NH / 256);
  const dim3 gridM(NH / 128, NB / 128);   // mfma gemm, M=1024
  const float invH = 1.0f / (float)NH;

  k_prep<<<dim3(HH / 256), dim3(256), 0, stream>>>(Wz1w, Wz2w, Wzoutw, S1b, S1Tb, S2b, S2Tb, so);

  // layer 0 (fp32: K=32 and K=512)
  k_gemm<0><<<gridB, blk2, 0, stream>>>(X,  Wz0w, HP, NDIM, NDIM, 1.f);
  k_gemm<1><<<gridB, blk2, 0, stream>>>(Cc, Wc0w, HP, NC,   NC,   1.f);
  k_act<<<gridE, dim3(256), 0, stream>>>(HP, Wz0b, Wc0b, nullptr, an0b, an0l, Z0b, G0, U0, 0);
  // layer 1
  k_mgemm<0><<<gridM, dim3(256), 0, stream>>>(Z0b, S1b, HP, nullptr, nullptr, nullptr, invH, NH, 0);
  k_gemm<1><<<gridB, blk2, 0, stream>>>(X,  Wx1w, HP, NDIM, NDIM, 1.f);
  k_gemm<1><<<gridB, blk2, 0, stream>>>(Cc, Wc1w, HP, NC,   NC,   1.f);
  k_act<<<gridE, dim3(256), 0, stream>>>(HP, Wz1b, Wx1b, Wc1b, an1b, an1l, Z1b, G1, U1, 1);
  // layer 2
  k_mgemm<0><<<gridM, dim3(256), 0, stream>>>(Z1b, S2b, HP, nullptr, nullptr, nullptr, invH, NH, 0);
  k_gemm<1><<<gridB, blk2, 0, stream>>>(X,  Wx2w, HP, NDIM, NDIM, 1.f);
  k_gemm<1><<<gridB, blk2, 0, stream>>>(Cc, Wc2w, HP, NC,   NC,   1.f);
  k_act2<<<gridE, dim3(256), 0, stream>>>(HP, Wz2b, Wx2b, Wc2b, an2b, an2l, so, D2g, D2u, D2gb);
  // backward sensitivities
  k_mgemm<0><<<gridM, dim3(256), 0, stream>>>(D2gb, S2Tb, T1, nullptr, nullptr, nullptr, invH, NH, 0);
  k_bw1<<<gridE, dim3(256), 0, stream>>>(T1, G1, U1, E1b, D1);
  k_mgemm<0><<<gridM, dim3(256), 0, stream>>>(E1b, S1Tb, T0, nullptr, nullptr, nullptr, invH, NH, 0);
  k_bw0<<<gridE, dim3(256), 0, stream>>>(T0, U0, D0);

  // Jacobian propagation (bf16 MFMA) + Gram assembly, chunked over samples
  const dim3 gridJ(NH / 128, CB * 32 / 128);
  const dim3 gridA((size_t)CB * 32 * NH / 256);
  for (int b0 = 0; b0 < NB; b0 += CB) {
    k_ahat1<<<gridA, dim3(256), 0, stream>>>(G0, Wz0w, Ah1, b0);
    k_mgemm<2><<<gridJ, dim3(256), 0, stream>>>(Ah1, S1b, Jh1, Ah2, G1, Wx1w, invH, NH, b0);
    k_mgemm<1><<<gridJ, dim3(256), 0, stream>>>(Ah2, S2b, Jh2, nullptr, nullptr, Wx2w, invH, NH, b0);
    k_assemble<<<dim3(CB), dim3(256), 0, stream>>>(Jh1, Jh2, D0, D1, D2u, D2g,
                                                   Wz0w, X, Wxoutw, w0, w1,
                                                   outF, outLD, b0);
  }
}

// Round 3
// 979.180 us; speedup vs baseline: 2.6480x; 1.0587x over previous
//
#include <hip/hip_runtime.h>

constexpr int NB   = 1024;  // batch
constexpr int NDIM = 32;    // x dim
constexpr int NH   = 1024;  // hidden dim
constexpr int NC   = 512;   // context dim

constexpr float INV_SQRT2PI = 0.3989422804014327f;
constexpr float SQRT_HALF   = 0.70710678118654752f;
constexpr float SQRT_HPI    = 1.2533141373155003f;

typedef __attribute__((ext_vector_type(8))) short short8;
typedef __attribute__((ext_vector_type(4))) float float4v;

__device__ __forceinline__ float sp_f(float x) {
  return (x > 20.f) ? x : log1pf(expf(x));
}

__device__ __forceinline__ short f2bf(float f) {
  union { float f; unsigned u; } x; x.f = f;
  const unsigned r = x.u + 0x7fffu + ((x.u >> 16) & 1u);
  return (short)(r >> 16);
}

__device__ __forceinline__ void async_ld16(const void* g, void* l) {
  __builtin_amdgcn_global_load_lds(
      (const __attribute__((address_space(1))) void*)g,
      (__attribute__((address_space(3))) void*)l, 16, 0, 0);
}

// ---------------- prep: softplus(Wz1/Wz2/Wzout)->bf16, Wc*->bf16, Cc->bf16, Wz0^T->bf16 ----------------
__global__ __launch_bounds__(256) void k_prep(
    const float* __restrict__ Wz1, const float* __restrict__ Wz2,
    const float* __restrict__ Wzout, const float* __restrict__ Wz0,
    const float* __restrict__ Wc0, const float* __restrict__ Wc1,
    const float* __restrict__ Wc2, const float* __restrict__ Cc,
    short* __restrict__ S1b, short* __restrict__ S1Tb,
    short* __restrict__ S2b, short* __restrict__ S2Tb,
    short* __restrict__ Wc0b, short* __restrict__ Wc1b, short* __restrict__ Wc2b,
    short* __restrict__ Ccb, short* __restrict__ W0Tb,
    float* __restrict__ so)
{
  const int idx = blockIdx.x * 256 + threadIdx.x;   // 0 .. NH*NH-1
  const int i = idx >> 10, p = idx & 1023;
  const float v1 = sp_f(Wz1[idx]);
  const short b1 = f2bf(v1);
  S1b[idx] = b1; S1Tb[p * NH + i] = b1;
  const float v2 = sp_f(Wz2[idx]);
  const short b2 = f2bf(v2);
  S2b[idx] = b2; S2Tb[p * NH + i] = b2;
  if (idx < NH) so[idx] = sp_f(Wzout[idx]);
  if (idx < NH * NC) {
    Wc0b[idx] = f2bf(Wc0[idx]);
    Wc1b[idx] = f2bf(Wc1[idx]);
    Wc2b[idx] = f2bf(Wc2[idx]);
  }
  if (idx < NB * NC) Ccb[idx] = f2bf(Cc[idx]);
  if (idx < NDIM * NH) {
    const int j = idx >> 10, pp = idx & 1023;   // out [32,1024]
    W0Tb[idx] = f2bf(Wz0[pp * NDIM + j]);
  }
}

// ---------------- fp32 tiled GEMM (K=32 X-terms only) ----------------
template<int EPI>  // 0: C=acc, 1: C+=acc
__global__ __launch_bounds__(256) void k_gemm(
    const float* __restrict__ A, const float* __restrict__ Bt,
    float* __restrict__ C, int K, int lda, float scale)
{
  __shared__ float As[16][68];
  __shared__ float Bs[16][68];
  const int tid  = threadIdx.y * 16 + threadIdx.x;
  const int arow = tid >> 2;
  const int acol = (tid & 3) << 2;
  const int m0 = blockIdx.y << 6;
  const int n0 = blockIdx.x << 6;

  float acc[4][4];
#pragma unroll
  for (int i = 0; i < 4; ++i)
#pragma unroll
    for (int j = 0; j < 4; ++j) acc[i][j] = 0.f;

  const int R = m0 + arow;
  for (int k0 = 0; k0 < K; k0 += 16) {
    const float4 av = *reinterpret_cast<const float4*>(&A[(size_t)R * lda + k0 + acol]);
    As[acol + 0][arow] = av.x; As[acol + 1][arow] = av.y;
    As[acol + 2][arow] = av.z; As[acol + 3][arow] = av.w;
    const float4 bv = *reinterpret_cast<const float4*>(&Bt[(size_t)(n0 + arow) * K + k0 + acol]);
    Bs[acol + 0][arow] = bv.x; Bs[acol + 1][arow] = bv.y;
    Bs[acol + 2][arow] = bv.z; Bs[acol + 3][arow] = bv.w;
    __syncthreads();
#pragma unroll
    for (int kk = 0; kk < 16; ++kk) {
      const float4 a  = *reinterpret_cast<const float4*>(&As[kk][threadIdx.y << 2]);
      const float4 bb = *reinterpret_cast<const float4*>(&Bs[kk][threadIdx.x << 2]);
      const float am[4] = {a.x, a.y, a.z, a.w};
      const float bn[4] = {bb.x, bb.y, bb.z, bb.w};
#pragma unroll
      for (int i2 = 0; i2 < 4; ++i2)
#pragma unroll
        for (int j2 = 0; j2 < 4; ++j2)
          acc[i2][j2] = fmaf(am[i2], bn[j2], acc[i2][j2]);
    }
    __syncthreads();
  }
#pragma unroll
  for (int i2 = 0; i2 < 4; ++i2) {
    const int row = m0 + (threadIdx.y << 2) + i2;
    const int col = n0 + (threadIdx.x << 2);
    float* cp = &C[(size_t)row * NH + col];
    float4 o;
    o.x = acc[i2][0] * scale; o.y = acc[i2][1] * scale;
    o.z = acc[i2][2] * scale; o.w = acc[i2][3] * scale;
    if constexpr (EPI == 1) {
      const float4 cur = *reinterpret_cast<const float4*>(cp);
      o.x += cur.x; o.y += cur.y; o.z += cur.z; o.w += cur.w;
    }
    *reinterpret_cast<float4*>(cp) = o;
  }
}

// ---------------- bf16 MFMA GEMM: acc = A[M,K]@Bt[1024,K]^T ----------------
// EPI 0: C  = acc*scale                      (fwd/bwd GEMMs, fp32 out)
// EPI 3: C += acc*scale                      (c-path accumulate into HP)
// EPI 1: (GEMM2) m = acc*scale + wepi;  o1=bf16(m), o2=bf16(m*dvec)                [M2,P2]
// EPI 2: (GEMM1) m = acc*scale + wepi;  o1=bf16(m), o2=bf16(m*gvec), o3=bf16(m*dvec) [M1,A2,P1]
template<int EPI>
__global__ __launch_bounds__(256) void k_mgemm(
    const short* __restrict__ A, const short* __restrict__ Bt,
    float* __restrict__ C,
    short* __restrict__ o1, short* __restrict__ o2, short* __restrict__ o3,
    const float* __restrict__ gvec, const float* __restrict__ dvec,
    const float* __restrict__ wepi,
    float scale, int K, int b0)
{
  __shared__ short As[128 * 32];
  __shared__ short Bs[128 * 32];
  const int tid  = threadIdx.x;
  const int wave = tid >> 6, lane = tid & 63;
  const int m0 = blockIdx.y << 7, n0 = blockIdx.x << 7;
  const int wm = (wave >> 1) << 6, wn = (wave & 1) << 6;
  const int qd = lane >> 4, md = lane & 15;

  float4v acc[4][4];
#pragma unroll
  for (int i = 0; i < 4; ++i)
#pragma unroll
    for (int j = 0; j < 4; ++j) acc[i][j] = (float4v)(0.f);

  const int sr = lane >> 2;
  const int sc = (lane & 3) << 3;

  for (int k0 = 0; k0 < K; k0 += 32) {
#pragma unroll
    for (int i = 0; i < 2; ++i) {
      const int ch  = wave * 2 + i;
      const int row = ch * 16 + sr;
      async_ld16(&A [(size_t)(m0 + row) * K + k0 + sc], &As[ch * 512]);
      async_ld16(&Bt[(size_t)(n0 + row) * K + k0 + sc], &Bs[ch * 512]);
    }
    __syncthreads();
    short8 af[4], bfr[4];
#pragma unroll
    for (int t = 0; t < 4; ++t) {
      af[t]  = *(const short8*)&As[(wm + t * 16 + md) * 32 + qd * 8];
      bfr[t] = *(const short8*)&Bs[(wn + t * 16 + md) * 32 + qd * 8];
    }
#pragma unroll
    for (int i = 0; i < 4; ++i)
#pragma unroll
      for (int j = 0; j < 4; ++j)
        acc[i][j] = __builtin_amdgcn_mfma_f32_16x16x32_bf16(af[i], bfr[j], acc[i][j], 0, 0, 0);
    __syncthreads();
  }

#pragma unroll
  for (int i = 0; i < 4; ++i) {
#pragma unroll
    for (int j = 0; j < 4; ++j) {
      const int colg = n0 + wn + j * 16 + md;
#pragma unroll
      for (int r = 0; r < 4; ++r) {
        const int rowg = m0 + wm + i * 16 + qd * 4 + r;
        float v = acc[i][j][r] * scale;
        const size_t ci = (size_t)rowg * NH + colg;
        if constexpr (EPI == 0) {
          C[ci] = v;
        } else if constexpr (EPI == 3) {
          C[ci] += v;
        } else {
          const int b = b0 + (rowg >> 5);
          v += wepi[colg * NDIM + (rowg & 31)];
          o1[ci] = f2bf(v);
          if constexpr (EPI == 1) {
            o2[ci] = f2bf(v * dvec[(size_t)b * NH + colg]);
          } else {  // EPI == 2
            o2[ci] = f2bf(v * gvec[(size_t)b * NH + colg]);
            o3[ci] = f2bf(v * dvec[(size_t)b * NH + colg]);
          }
        }
      }
    }
  }
}

// ---------------- activation (layers 0/1): writes Zbf (bf16), G, U ----------------
__global__ __launch_bounds__(256) void k_act(
    const float* __restrict__ HP,
    const float* __restrict__ bA, const float* __restrict__ bB,
    const float* __restrict__ bC,
    const float* __restrict__ anb, const float* __restrict__ anl,
    short* __restrict__ Zbf, float* __restrict__ G, float* __restrict__ U,
    int hasC)
{
  const int idx = blockIdx.x * 256 + threadIdx.x;
  const int i = idx & 1023;
  float bias = bA[i] + bB[i] + anb[i];
  if (hasC) bias += bC[i];
  const float el = expf(anl[i]);
  const float a = (HP[idx] + bias) * el;
  const float pdf = expf(-0.5f * a * a);
  const float er = erff(a * SQRT_HALF);
  Zbf[idx] = f2bf((SQRT_HPI * a * er + pdf + SQRT_HPI * a) * INV_SQRT2PI);
  G[idx] = 0.5f * (1.f + er) * el;
  U[idx] = pdf * INV_SQRT2PI * el * el;
}

// ---------------- activation (layer 2): D2u fp32, D2g bf16 ----------------
__global__ __launch_bounds__(256) void k_act2(
    const float* __restrict__ HP,
    const float* __restrict__ bA, const float* __restrict__ bB,
    const float* __restrict__ bC,
    const float* __restrict__ anb, const float* __restrict__ anl,
    const float* __restrict__ so,
    float* __restrict__ D2u, short* __restrict__ D2gbf)
{
  const int idx = blockIdx.x * 256 + threadIdx.x;
  const int i = idx & 1023;
  const float bias = bA[i] + bB[i] + bC[i] + anb[i];
  const float el = expf(anl[i]);
  const float a = (HP[idx] + bias) * el;
  const float pdf = expf(-0.5f * a * a);
  const float er = erff(a * SQRT_HALF);
  const float g = 0.5f * (1.f + er) * el;
  const float u = pdf * INV_SQRT2PI * el * el;
  const float t2 = so[i] * (1.f / NH);
  D2u[idx] = t2 * u;
  D2gbf[idx] = f2bf(t2 * g);
}

__global__ __launch_bounds__(256) void k_bw1(
    const float* __restrict__ T1, const float* __restrict__ G1,
    const float* __restrict__ U1,
    short* __restrict__ E1bf, float* __restrict__ D1)
{
  const int idx = blockIdx.x * 256 + threadIdx.x;
  const float t = T1[idx];
  E1bf[idx] = f2bf(t * G1[idx]);
  D1[idx] = t * U1[idx];
}

__global__ __launch_bounds__(256) void k_bw0(
    const float* __restrict__ T0, const float* __restrict__ U0,
    float* __restrict__ D0)
{
  const int idx = blockIdx.x * 256 + threadIdx.x;
  D0[idx] = T0[idx] * U0[idx];
}

// ---------------- Ah1[r,p] = bf16(G0*Wz0^T), P0[r,p] = bf16(D0*Wz0^T) ----------------
__global__ __launch_bounds__(256) void k_scale0(
    const float* __restrict__ G0, const float* __restrict__ D0,
    const float* __restrict__ Wz0,
    short* __restrict__ Ah1, short* __restrict__ P0, int b0)
{
  const int idx = blockIdx.x * 256 + threadIdx.x;
  const int p = idx & 1023, r = idx >> 10;
  const int b = b0 + (r >> 5), j = r & 31;
  const float w = Wz0[p * NDIM + j];
  Ah1[idx] = f2bf(G0[(size_t)b * NH + p] * w);
  P0[idx]  = f2bf(D0[(size_t)b * NH + p] * w);
}

// ---------------- per-sample MFMA Gram + v + f + Cholesky logdet ----------------
template<bool DOV>
__device__ __forceinline__ void gram_layer(
    const short* __restrict__ Arow, const short* __restrict__ Brow,
    const short* __restrict__ d2g,
    float4v& acc, float4v& vacc,
    int wm, int wn, int qd, int md, bool vwave)
{
#pragma unroll 4
  for (int k0 = 0; k0 < NH; k0 += 32) {
    const short8 af  = *(const short8*)&Arow[(size_t)(wm + md) * NH + k0 + qd * 8];
    const short8 bfr = *(const short8*)&Brow[(size_t)(wn + md) * NH + k0 + qd * 8];
    acc = __builtin_amdgcn_mfma_f32_16x16x32_bf16(af, bfr, acc, 0, 0, 0);
    if constexpr (DOV) {
      if (vwave) {
        short8 dv = {};
        if (md == 0) dv = *(const short8*)&d2g[k0 + qd * 8];
        vacc = __builtin_amdgcn_mfma_f32_16x16x32_bf16(dv, bfr, vacc, 0, 0, 0);
      }
    }
  }
}

__global__ __launch_bounds__(256) void k_gram(
    const short* __restrict__ P0, const short* __restrict__ W0T,
    const short* __restrict__ M1, const short* __restrict__ P1,
    const short* __restrict__ M2, const short* __restrict__ P2,
    const short* __restrict__ D2gb,
    const float* __restrict__ X, const float* __restrict__ Wxout,
    const float* __restrict__ w0p, const float* __restrict__ w1p,
    float* __restrict__ outF, float* __restrict__ outLD, int b0)
{
  const int bl = blockIdx.x;
  const int b = b0 + bl;
  const int tid = threadIdx.x;
  const int wave = tid >> 6, lane = tid & 63;
  const int wm = (wave >> 1) << 4, wn = (wave & 1) << 4;
  const int qd = lane >> 4, md = lane & 15;
  const bool vwave = (wave < 2);

  const size_t rb = (size_t)bl * 32 * NH;

  float4v acc = (float4v)(0.f);
  float4v vacc = (float4v)(0.f);

  gram_layer<false>(P0 + rb, W0T,     nullptr,               acc, vacc, wm, wn, qd, md, false);
  gram_layer<false>(P1 + rb, M1 + rb, nullptr,               acc, vacc, wm, wn, qd, md, false);
  gram_layer<true >(P2 + rb, M2 + rb, D2gb + (size_t)b * NH, acc, vacc, wm, wn, qd, md, vwave);

  __shared__ float sH[32][33];
  __shared__ float sv[32];
  __shared__ float sred[32];

  const float spw0 = sp_f(w0p[0]);
  const float spw1 = sp_f(w1p[0]);

#pragma unroll
  for (int r = 0; r < 4; ++r) {
    const int row = wm + qd * 4 + r;   // C/D layout: row = (lane>>4)*4 + reg
    const int col = wn + md;           //             col = lane & 15
    float g = acc[r] * spw1;
    if (row == col) g += spw0;
    sH[row][col] = g;
  }
  if (vwave && qd == 0) sv[wn + md] = vacc[0];
  __syncthreads();

  if (tid < 32) {
    outF[(size_t)b * NDIM + tid] =
        spw1 * (sv[tid] + Wxout[tid]) + spw0 * X[(size_t)b * NDIM + tid];
  }

  float ldacc = 0.f;
  for (int c = 0; c < 32; ++c) {
    if (tid >= c && tid < 32) {
      float s = sH[tid][c];
      for (int m = 0; m < c; ++m) s -= sH[tid][m] * sH[c][m];
      sred[tid] = s;
    }
    __syncthreads();
    const float sc = sred[c];
    if (tid >= c && tid < 32) {
      const float lcc = sqrtf(sc);
      sH[tid][c] = (tid == c) ? lcc : sred[tid] / lcc;
    }
    ldacc += logf(sc);
    __syncthreads();
  }
  if (tid == 0) outLD[b] = ldacc;
}

// ---------------- launcher ----------------
extern "C" void kernel_launch(void* const* d_in, const int* in_sizes, int n_in,
                              void* d_out, int out_size, void* d_ws, size_t ws_size,
                              hipStream_t stream)
{
  const float* X    = (const float*)d_in[0];
  const float* Cc   = (const float*)d_in[1];
  const float* w0   = (const float*)d_in[2];
  const float* w1   = (const float*)d_in[3];
  const float* Wz0w = (const float*)d_in[4];
  const float* Wz0b = (const float*)d_in[5];
  const float* Wc0w = (const float*)d_in[6];
  const float* Wc0b = (const float*)d_in[7];
  const float* an0b = (const float*)d_in[8];
  const float* an0l = (const float*)d_in[9];
  const float* Wz1w = (const float*)d_in[10];
  const float* Wz1b = (const float*)d_in[11];
  const float* Wx1w = (const float*)d_in[12];
  const float* Wx1b = (const float*)d_in[13];
  const float* Wc1w = (const float*)d_in[14];
  const float* Wc1b = (const float*)d_in[15];
  const float* an1b = (const float*)d_in[16];
  const float* an1l = (const float*)d_in[17];
  const float* Wz2w = (const float*)d_in[18];
  const float* Wz2b = (const float*)d_in[19];
  const float* Wx2w = (const float*)d_in[20];
  const float* Wx2b = (const float*)d_in[21];
  const float* Wc2w = (const float*)d_in[22];
  const float* Wc2b = (const float*)d_in[23];
  const float* an2b = (const float*)d_in[24];
  const float* an2l = (const float*)d_in[25];
  const float* Wzoutw = (const float*)d_in[26];
  const float* Wxoutw = (const float*)d_in[27];
  // d_in[28] (Wcout_w): constant in x -> no grad/Hessian contribution.

  float* ws = (float*)d_ws;
  size_t off = 0;
  auto alloc = [&](size_t n) {
    float* p = ws + off; off += (n + 3) & ~(size_t)3; return p;
  };
  const size_t HH = (size_t)NH * NH;
  const size_t BH = (size_t)NB * NH;

  short* S1b  = (short*)alloc(HH / 2);
  short* S2b  = (short*)alloc(HH / 2);
  short* S1Tb = (short*)alloc(HH / 2);
  short* S2Tb = (short*)alloc(HH / 2);
  short* Wc0bb = (short*)alloc((size_t)NH * NC / 2);
  short* Wc1bb = (short*)alloc((size_t)NH * NC / 2);
  short* Wc2bb = (short*)alloc((size_t)NH * NC / 2);
  short* Ccb  = (short*)alloc((size_t)NB * NC / 2);
  short* W0Tb = (short*)alloc((size_t)NDIM * NH / 2);
  float* so   = alloc(NH);
  float* HP   = alloc(BH);
  short* Z0b  = (short*)alloc(BH / 2);
  short* Z1b  = (short*)alloc(BH / 2);
  float* G0   = alloc(BH);
  float* U0   = alloc(BH);
  float* G1   = alloc(BH);
  float* U1   = alloc(BH);
  float* D2u  = alloc(BH);
  short* D2gb = (short*)alloc(BH / 2);
  float* T1   = alloc(BH);
  short* E1b  = (short*)alloc(BH / 2);
  float* D1   = alloc(BH);
  float* T0   = alloc(BH);
  float* D0   = alloc(BH);

  // per-chunk bf16 buffers: Ah1, P0, M1, A2, P1, M2, P2
  const size_t avail_f = ws_size / sizeof(float);
  int CB = 32;
  const int cands[5] = {512, 256, 128, 64, 32};
  for (int ci = 0; ci < 5; ++ci) {
    const size_t need = off + 7 * ((size_t)cands[ci] * 32 * NH / 2 + 4) + 64;
    if (need <= avail_f) { CB = cands[ci]; break; }
  }
  const size_t chunk_sh = (size_t)CB * 32 * NH;   // shorts per buffer
  short* Ah1 = (short*)alloc(chunk_sh / 2);
  short* P0b = (short*)alloc(chunk_sh / 2);
  short* M1b = (short*)alloc(chunk_sh / 2);
  short* A2b = (short*)alloc(chunk_sh / 2);
  short* P1b = (short*)alloc(chunk_sh / 2);
  short* M2b = (short*)alloc(chunk_sh / 2);
  short* P2b = (short*)alloc(chunk_sh / 2);

  float* outF  = (float*)d_out;
  float* outLD = (float*)d_out + NB * NDIM;

  const dim3 blk2(16, 16);
  const dim3 gridX(16, NB / 64);          // fp32 gemm, K=32 terms
  const dim3 gridE(NB * NH / 256);
  const dim3 gridM(NH / 128, NB / 128);   // mfma gemm over [1024 x 1024]
  const float invH = 1.0f / (float)NH;

  k_prep<<<dim3(HH / 256), dim3(256), 0, stream>>>(
      Wz1w, Wz2w, Wzoutw, Wz0w, Wc0w, Wc1w, Wc2w, Cc,
      S1b, S1Tb, S2b, S2Tb, Wc0bb, Wc1bb, Wc2bb, Ccb, W0Tb, so);

  // layer 0: HP = X@Wz0^T + Cc@Wc0^T
  k_gemm<0><<<gridX, blk2, 0, stream>>>(X, Wz0w, HP, NDIM, NDIM, 1.f);
  k_mgemm<3><<<gridM, dim3(256), 0, stream>>>(Ccb, Wc0bb, HP, nullptr, nullptr, nullptr,
                                              nullptr, nullptr, nullptr, 1.f, NC, 0);
  k_act<<<gridE, dim3(256), 0, stream>>>(HP, Wz0b, Wc0b, nullptr, an0b, an0l, Z0b, G0, U0, 0);
  // layer 1: HP = Z0@S1^T/H + X@Wx1^T + Cc@Wc1^T
  k_mgemm<0><<<gridM, dim3(256), 0, stream>>>(Z0b, S1b, HP, nullptr, nullptr, nullptr,
                                              nullptr, nullptr, nullptr, invH, NH, 0);
  k_gemm<1><<<gridX, blk2, 0, stream>>>(X, Wx1w, HP, NDIM, NDIM, 1.f);
  k_mgemm<3><<<gridM, dim3(256), 0, stream>>>(Ccb, Wc1bb, HP, nullptr, nullptr, nullptr,
                                              nullptr, nullptr, nullptr, 1.f, NC, 0);
  k_act<<<gridE, dim3(256), 0, stream>>>(HP, Wz1b, Wx1b, Wc1b, an1b, an1l, Z1b, G1, U1, 1);
  // layer 2
  k_mgemm<0><<<gridM, dim3(256), 0, stream>>>(Z1b, S2b, HP, nullptr, nullptr, nullptr,
                                              nullptr, nullptr, nullptr, invH, NH, 0);
  k_gemm<1><<<gridX, blk2, 0, stream>>>(X, Wx2w, HP, NDIM, NDIM, 1.f);
  k_mgemm<3><<<gridM, dim3(256), 0, stream>>>(Ccb, Wc2bb, HP, nullptr, nullptr, nullptr,
                                              nullptr, nullptr, nullptr, 1.f, NC, 0);
  k_act2<<<gridE, dim3(256), 0, stream>>>(HP, Wz2b, Wx2b, Wc2b, an2b, an2l, so, D2u, D2gb);
  // backward sensitivities
  k_mgemm<0><<<gridM, dim3(256), 0, stream>>>(D2gb, S2Tb, T1, nullptr, nullptr, nullptr,
                                              nullptr, nullptr, nullptr, invH, NH, 0);
  k_bw1<<<gridE, dim3(256), 0, stream>>>(T1, G1, U1, E1b, D1);
  k_mgemm<0><<<gridM, dim3(256), 0, stream>>>(E1b, S1Tb, T0, nullptr, nullptr, nullptr,
                                              nullptr, nullptr, nullptr, invH, NH, 0);
  k_bw0<<<gridE, dim3(256), 0, stream>>>(T0, U0, D0);

  // Jacobian propagation (bf16 MFMA, scaled bf16 epilogues) + MFMA Gram, chunked
  const dim3 gridJ(NH / 128, CB * 32 / 128);
  const dim3 gridS((size_t)CB * 32 * NH / 256);
  for (int b0 = 0; b0 < NB; b0 += CB) {
    k_scale0<<<gridS, dim3(256), 0, stream>>>(G0, D0, Wz0w, Ah1, P0b, b0);
    k_mgemm<2><<<gridJ, dim3(256), 0, stream>>>(Ah1, S1b, nullptr, M1b, A2b, P1b,
                                                G1, D1, Wx1w, invH, NH, b0);
    k_mgemm<1><<<gridJ, dim3(256), 0, stream>>>(A2b, S2b, nullptr, M2b, P2b, nullptr,
                                                nullptr, D2u, Wx2w, invH, NH, b0);
    k_gram<<<dim3(CB), dim3(256), 0, stream>>>(P0b, W0Tb, M1b, P1b, M2b, P2b, D2gb,
                                               X, Wxoutw, w0, w1, outF, outLD, b0);
  }
}

// Round 4
// 915.213 us; speedup vs baseline: 2.8331x; 1.0699x over previous
//
#include <hip/hip_runtime.h>

constexpr int NB   = 1024;  // batch
constexpr int NDIM = 32;    // x dim
constexpr int NH   = 1024;  // hidden dim
constexpr int NC   = 512;   // context dim
constexpr int NS   = 8;     // K-splits in k_gram

constexpr float INV_SQRT2PI = 0.3989422804014327f;
constexpr float SQRT_HALF   = 0.70710678118654752f;
constexpr float SQRT_HPI    = 1.2533141373155003f;

typedef __attribute__((ext_vector_type(8))) short short8;
typedef __attribute__((ext_vector_type(4))) float float4v;

__device__ __forceinline__ float sp_f(float x) {
  return (x > 20.f) ? x : log1pf(expf(x));
}

__device__ __forceinline__ short f2bf(float f) {
  union { float f; unsigned u; } x; x.f = f;
  const unsigned r = x.u + 0x7fffu + ((x.u >> 16) & 1u);
  return (short)(r >> 16);
}

__device__ __forceinline__ float bf2f(short s) {
  union { unsigned u; float f; } c;
  c.u = ((unsigned)(unsigned short)s) << 16;
  return c.f;
}

__device__ __forceinline__ void async_ld16(const void* g, void* l) {
  __builtin_amdgcn_global_load_lds(
      (const __attribute__((address_space(1))) void*)g,
      (__attribute__((address_space(3))) void*)l, 16, 0, 0);
}

// ---------------- prep: softplus(Wz1/Wz2/Wzout)->bf16, Wc*->bf16, Cc->bf16, Wz0^T->bf16 ----------------
__global__ __launch_bounds__(256) void k_prep(
    const float* __restrict__ Wz1, const float* __restrict__ Wz2,
    const float* __restrict__ Wzout, const float* __restrict__ Wz0,
    const float* __restrict__ Wc0, const float* __restrict__ Wc1,
    const float* __restrict__ Wc2, const float* __restrict__ Cc,
    short* __restrict__ S1b, short* __restrict__ S1Tb,
    short* __restrict__ S2b, short* __restrict__ S2Tb,
    short* __restrict__ Wc0b, short* __restrict__ Wc1b, short* __restrict__ Wc2b,
    short* __restrict__ Ccb, short* __restrict__ W0Tb,
    float* __restrict__ so)
{
  const int idx = blockIdx.x * 256 + threadIdx.x;   // 0 .. NH*NH-1
  const int i = idx >> 10, p = idx & 1023;
  const float v1 = sp_f(Wz1[idx]);
  const short b1 = f2bf(v1);
  S1b[idx] = b1; S1Tb[p * NH + i] = b1;
  const float v2 = sp_f(Wz2[idx]);
  const short b2 = f2bf(v2);
  S2b[idx] = b2; S2Tb[p * NH + i] = b2;
  if (idx < NH) so[idx] = sp_f(Wzout[idx]);
  if (idx < NH * NC) {
    Wc0b[idx] = f2bf(Wc0[idx]);
    Wc1b[idx] = f2bf(Wc1[idx]);
    Wc2b[idx] = f2bf(Wc2[idx]);
  }
  if (idx < NB * NC) Ccb[idx] = f2bf(Cc[idx]);
  if (idx < NDIM * NH) {
    const int j = idx >> 10, pp = idx & 1023;   // out [32,1024]
    W0Tb[idx] = f2bf(Wz0[pp * NDIM + j]);
  }
}

// ---------------- fp32 tiled GEMM (K=32 X-terms only) ----------------
template<int EPI>  // 0: C=acc, 1: C+=acc
__global__ __launch_bounds__(256) void k_gemm(
    const float* __restrict__ A, const float* __restrict__ Bt,
    float* __restrict__ C, int K, int lda, float scale)
{
  __shared__ float As[16][68];
  __shared__ float Bs[16][68];
  const int tid  = threadIdx.y * 16 + threadIdx.x;
  const int arow = tid >> 2;
  const int acol = (tid & 3) << 2;
  const int m0 = blockIdx.y << 6;
  const int n0 = blockIdx.x << 6;

  float acc[4][4];
#pragma unroll
  for (int i = 0; i < 4; ++i)
#pragma unroll
    for (int j = 0; j < 4; ++j) acc[i][j] = 0.f;

  const int R = m0 + arow;
  for (int k0 = 0; k0 < K; k0 += 16) {
    const float4 av = *reinterpret_cast<const float4*>(&A[(size_t)R * lda + k0 + acol]);
    As[acol + 0][arow] = av.x; As[acol + 1][arow] = av.y;
    As[acol + 2][arow] = av.z; As[acol + 3][arow] = av.w;
    const float4 bv = *reinterpret_cast<const float4*>(&Bt[(size_t)(n0 + arow) * K + k0 + acol]);
    Bs[acol + 0][arow] = bv.x; Bs[acol + 1][arow] = bv.y;
    Bs[acol + 2][arow] = bv.z; Bs[acol + 3][arow] = bv.w;
    __syncthreads();
#pragma unroll
    for (int kk = 0; kk < 16; ++kk) {
      const float4 a  = *reinterpret_cast<const float4*>(&As[kk][threadIdx.y << 2]);
      const float4 bb = *reinterpret_cast<const float4*>(&Bs[kk][threadIdx.x << 2]);
      const float am[4] = {a.x, a.y, a.z, a.w};
      const float bn[4] = {bb.x, bb.y, bb.z, bb.w};
#pragma unroll
      for (int i2 = 0; i2 < 4; ++i2)
#pragma unroll
        for (int j2 = 0; j2 < 4; ++j2)
          acc[i2][j2] = fmaf(am[i2], bn[j2], acc[i2][j2]);
    }
    __syncthreads();
  }
#pragma unroll
  for (int i2 = 0; i2 < 4; ++i2) {
    const int row = m0 + (threadIdx.y << 2) + i2;
    const int col = n0 + (threadIdx.x << 2);
    float* cp = &C[(size_t)row * NH + col];
    float4 o;
    o.x = acc[i2][0] * scale; o.y = acc[i2][1] * scale;
    o.z = acc[i2][2] * scale; o.w = acc[i2][3] * scale;
    if constexpr (EPI == 1) {
      const float4 cur = *reinterpret_cast<const float4*>(cp);
      o.x += cur.x; o.y += cur.y; o.z += cur.z; o.w += cur.w;
    }
    *reinterpret_cast<float4*>(cp) = o;
  }
}

// ---------------- bf16 MFMA GEMM, 128x128 tile (Jacobian GEMMs) ----------------
// EPI 1: (GEMM2) m = acc*scale + wepi;  o1 = bf16(m * sqrt(dvec))            [Q2]
// EPI 2: (GEMM1) m = acc*scale + wepi;  o1 = bf16(m * sqrt(dvec)), o2 = bf16(m * gvec)  [Q1, A2]
template<int EPI>
__global__ __launch_bounds__(256) void k_mgemm(
    const short* __restrict__ A, const short* __restrict__ Bt,
    short* __restrict__ o1, short* __restrict__ o2,
    const float* __restrict__ gvec, const float* __restrict__ dvec,
    const float* __restrict__ wepi,
    float scale, int K, int b0)
{
  __shared__ short As[128 * 32];
  __shared__ short Bs[128 * 32];
  const int tid  = threadIdx.x;
  const int wave = tid >> 6, lane = tid & 63;
  const int m0 = blockIdx.y << 7, n0 = blockIdx.x << 7;
  const int wm = (wave >> 1) << 6, wn = (wave & 1) << 6;
  const int qd = lane >> 4, md = lane & 15;

  float4v acc[4][4];
#pragma unroll
  for (int i = 0; i < 4; ++i)
#pragma unroll
    for (int j = 0; j < 4; ++j) acc[i][j] = (float4v)(0.f);

  const int sr = lane >> 2;
  const int sc = (lane & 3) << 3;

  for (int k0 = 0; k0 < K; k0 += 32) {
#pragma unroll
    for (int i = 0; i < 2; ++i) {
      const int ch  = wave * 2 + i;
      const int row = ch * 16 + sr;
      async_ld16(&A [(size_t)(m0 + row) * K + k0 + sc], &As[ch * 512]);
      async_ld16(&Bt[(size_t)(n0 + row) * K + k0 + sc], &Bs[ch * 512]);
    }
    __syncthreads();
    short8 af[4], bfr[4];
#pragma unroll
    for (int t = 0; t < 4; ++t) {
      af[t]  = *(const short8*)&As[(wm + t * 16 + md) * 32 + qd * 8];
      bfr[t] = *(const short8*)&Bs[(wn + t * 16 + md) * 32 + qd * 8];
    }
#pragma unroll
    for (int i = 0; i < 4; ++i)
#pragma unroll
      for (int j = 0; j < 4; ++j)
        acc[i][j] = __builtin_amdgcn_mfma_f32_16x16x32_bf16(af[i], bfr[j], acc[i][j], 0, 0, 0);
    __syncthreads();
  }

#pragma unroll
  for (int i = 0; i < 4; ++i) {
#pragma unroll
    for (int j = 0; j < 4; ++j) {
      const int colg = n0 + wn + j * 16 + md;
#pragma unroll
      for (int r = 0; r < 4; ++r) {
        const int rowg = m0 + wm + i * 16 + qd * 4 + r;
        const int b = b0 + (rowg >> 5);
        float v = acc[i][j][r] * scale + wepi[colg * NDIM + (rowg & 31)];
        const size_t ci = (size_t)rowg * NH + colg;
        const float dq = sqrtf(fmaxf(dvec[(size_t)b * NH + colg], 0.f));
        o1[ci] = f2bf(v * dq);
        if constexpr (EPI == 2)
          o2[ci] = f2bf(v * gvec[(size_t)b * NH + colg]);
      }
    }
  }
}

// ---------------- bf16 MFMA GEMM, 64x64 tile (fwd/bwd/c-path, M=N=1024) ----------------
template<int EPI>  // 0: C = acc*scale ; 3: C += acc*scale
__global__ __launch_bounds__(256) void k_mgemm64(
    const short* __restrict__ A, const short* __restrict__ Bt,
    float* __restrict__ C, float scale, int K)
{
  __shared__ short As[64 * 32];
  __shared__ short Bs[64 * 32];
  const int tid  = threadIdx.x;
  const int wave = tid >> 6, lane = tid & 63;
  const int m0 = blockIdx.y << 6, n0 = blockIdx.x << 6;
  const int wm = (wave >> 1) << 5, wn = (wave & 1) << 5;
  const int qd = lane >> 4, md = lane & 15;
  const int sr = lane >> 2;
  const int sc = (lane & 3) << 3;

  float4v acc[2][2];
#pragma unroll
  for (int i = 0; i < 2; ++i)
#pragma unroll
    for (int j = 0; j < 2; ++j) acc[i][j] = (float4v)(0.f);

  for (int k0 = 0; k0 < K; k0 += 32) {
    const int row = wave * 16 + sr;
    async_ld16(&A [(size_t)(m0 + row) * K + k0 + sc], &As[wave * 512]);
    async_ld16(&Bt[(size_t)(n0 + row) * K + k0 + sc], &Bs[wave * 512]);
    __syncthreads();
    short8 af[2], bfr[2];
#pragma unroll
    for (int t = 0; t < 2; ++t) {
      af[t]  = *(const short8*)&As[(wm + t * 16 + md) * 32 + qd * 8];
      bfr[t] = *(const short8*)&Bs[(wn + t * 16 + md) * 32 + qd * 8];
    }
#pragma unroll
    for (int i = 0; i < 2; ++i)
#pragma unroll
      for (int j = 0; j < 2; ++j)
        acc[i][j] = __builtin_amdgcn_mfma_f32_16x16x32_bf16(af[i], bfr[j], acc[i][j], 0, 0, 0);
    __syncthreads();
  }

#pragma unroll
  for (int i = 0; i < 2; ++i) {
#pragma unroll
    for (int j = 0; j < 2; ++j) {
      const int colg = n0 + wn + j * 16 + md;
#pragma unroll
      for (int r = 0; r < 2 * 2; ++r) {}  // (no-op; keep structure simple)
#pragma unroll
      for (int r = 0; r < 4; ++r) {
        const int rowg = m0 + wm + i * 16 + qd * 4 + r;
        const size_t ci = (size_t)rowg * NH + colg;
        const float v = acc[i][j][r] * scale;
        if constexpr (EPI == 0) C[ci] = v;
        else                    C[ci] += v;
      }
    }
  }
}

// ---------------- activation (layers 0/1): writes Zbf (bf16), G, U ----------------
__global__ __launch_bounds__(256) void k_act(
    const float* __restrict__ HP,
    const float* __restrict__ bA, const float* __restrict__ bB,
    const float* __restrict__ bC,
    const float* __restrict__ anb, const float* __restrict__ anl,
    short* __restrict__ Zbf, float* __restrict__ G, float* __restrict__ U,
    int hasC)
{
  const int idx = blockIdx.x * 256 + threadIdx.x;
  const int i = idx & 1023;
  float bias = bA[i] + bB[i] + anb[i];
  if (hasC) bias += bC[i];
  const float el = expf(anl[i]);
  const float a = (HP[idx] + bias) * el;
  const float pdf = expf(-0.5f * a * a);
  const float er = erff(a * SQRT_HALF);
  Zbf[idx] = f2bf((SQRT_HPI * a * er + pdf + SQRT_HPI * a) * INV_SQRT2PI);
  G[idx] = 0.5f * (1.f + er) * el;
  U[idx] = pdf * INV_SQRT2PI * el * el;
}

// ---------------- activation (layer 2): D2u fp32, D2g bf16 ----------------
__global__ __launch_bounds__(256) void k_act2(
    const float* __restrict__ HP,
    const float* __restrict__ bA, const float* __restrict__ bB,
    const float* __restrict__ bC,
    const float* __restrict__ anb, const float* __restrict__ anl,
    const float* __restrict__ so,
    float* __restrict__ D2u, short* __restrict__ D2gbf)
{
  const int idx = blockIdx.x * 256 + threadIdx.x;
  const int i = idx & 1023;
  const float bias = bA[i] + bB[i] + bC[i] + anb[i];
  const float el = expf(anl[i]);
  const float a = (HP[idx] + bias) * el;
  const float pdf = expf(-0.5f * a * a);
  const float er = erff(a * SQRT_HALF);
  const float g = 0.5f * (1.f + er) * el;
  const float u = pdf * INV_SQRT2PI * el * el;
  const float t2 = so[i] * (1.f / NH);
  D2u[idx] = t2 * u;
  D2gbf[idx] = f2bf(t2 * g);
}

__global__ __launch_bounds__(256) void k_bw1(
    const float* __restrict__ T1, const float* __restrict__ G1,
    const float* __restrict__ U1,
    short* __restrict__ E1bf, float* __restrict__ D1)
{
  const int idx = blockIdx.x * 256 + threadIdx.x;
  const float t = T1[idx];
  E1bf[idx] = f2bf(t * G1[idx]);
  D1[idx] = t * U1[idx];
}

// D0 = T0*U0 (fp32), GT0b = bf16(T0*G0)
__global__ __launch_bounds__(256) void k_bw0(
    const float* __restrict__ T0, const float* __restrict__ U0,
    const float* __restrict__ G0,
    float* __restrict__ D0, short* __restrict__ GT0b)
{
  const int idx = blockIdx.x * 256 + threadIdx.x;
  const float t = T0[idx];
  D0[idx] = t * U0[idx];
  GT0b[idx] = f2bf(t * G0[idx]);
}

// ---------------- Ah1[r,p] = bf16(G0[b,p] * Wz0[p, r&31]) ----------------
__global__ __launch_bounds__(256) void k_scale0(
    const float* __restrict__ G0, const float* __restrict__ Wz0,
    short* __restrict__ Ah1, int b0)
{
  const int idx = blockIdx.x * 256 + threadIdx.x;
  const int p = idx & 1023, r = idx >> 10;
  const int b = b0 + (r >> 5), j = r & 31;
  Ah1[idx] = f2bf(G0[(size_t)b * NH + p] * Wz0[p * NDIM + j]);
}

// ---------------- f = sp(w1)*(W0^T(g0*t0) + Wx1^T e1 + Wx2^T d2g + Wxout) + sp(w0)*x ----------------
__global__ __launch_bounds__(128) void k_fvec(
    const short* __restrict__ GT0b, const short* __restrict__ E1b,
    const short* __restrict__ D2gb,
    const float* __restrict__ W0, const float* __restrict__ Wx1,
    const float* __restrict__ Wx2,
    const float* __restrict__ X, const float* __restrict__ Wxout,
    const float* __restrict__ w0p, const float* __restrict__ w1p,
    float* __restrict__ outF)
{
  const int s = blockIdx.x * 4 + (threadIdx.x >> 5);
  const int j = threadIdx.x & 31;
  const size_t sb = (size_t)s * NH;
  float acc = 0.f;
  for (int k = 0; k < NH; k += 4) {
#pragma unroll
    for (int t = 0; t < 4; ++t) {
      const int kk = k + t;
      acc += bf2f(GT0b[sb + kk]) * W0[kk * NDIM + j]
           + bf2f(E1b[sb + kk])  * Wx1[kk * NDIM + j]
           + bf2f(D2gb[sb + kk]) * Wx2[kk * NDIM + j];
    }
  }
  const float spw0 = sp_f(w0p[0]);
  const float spw1 = sp_f(w1p[0]);
  outF[(size_t)s * NDIM + j] =
      spw1 * (acc + Wxout[j]) + spw0 * X[(size_t)s * NDIM + j];
}

// ---------------- K-split per-sample Gram partials (no LDS, no barriers) ----------------
__global__ __launch_bounds__(256) void k_gram(
    const short* __restrict__ Q1, const short* __restrict__ Q2,
    const short* __restrict__ W0T, const float* __restrict__ D0,
    float* __restrict__ partH, int b0)
{
  const int ns = blockIdx.x, bl = blockIdx.y;
  const int b = b0 + bl;
  const int wave = threadIdx.x >> 6, lane = threadIdx.x & 63;
  const int wm = (wave >> 1) << 4, wn = (wave & 1) << 4;
  const int qd = lane >> 4, md = lane & 15;
  const int kbeg = ns << 7;           // ns * 128
  const size_t rb = (size_t)bl * 32 * NH;

  float4v acc = (float4v)(0.f);

  // layer 0: Gram0 = W0^T diag(D0) W0  (scale A-side by D0 in registers)
  for (int k0 = kbeg; k0 < kbeg + 128; k0 += 32) {
    const int kk = k0 + qd * 8;
    const short8 ar = *(const short8*)&W0T[(size_t)(wm + md) * NH + kk];
    float dd[8];
    *(float4*)&dd[0] = *(const float4*)&D0[(size_t)b * NH + kk];
    *(float4*)&dd[4] = *(const float4*)&D0[(size_t)b * NH + kk + 4];
    short8 af;
#pragma unroll
    for (int e = 0; e < 8; ++e) af[e] = f2bf(bf2f(ar[e]) * dd[e]);
    const short8 bfr = *(const short8*)&W0T[(size_t)(wn + md) * NH + kk];
    acc = __builtin_amdgcn_mfma_f32_16x16x32_bf16(af, bfr, acc, 0, 0, 0);
  }
  // layers 1,2: Gram = Q Q^T (Q pre-scaled by sqrt(D))
#pragma unroll
  for (int l = 0; l < 2; ++l) {
    const short* Q = (l == 0) ? Q1 : Q2;
    for (int k0 = kbeg; k0 < kbeg + 128; k0 += 32) {
      const int kk = k0 + qd * 8;
      const short8 af  = *(const short8*)&Q[rb + (size_t)(wm + md) * NH + kk];
      const short8 bfr = *(const short8*)&Q[rb + (size_t)(wn + md) * NH + kk];
      acc = __builtin_amdgcn_mfma_f32_16x16x32_bf16(af, bfr, acc, 0, 0, 0);
    }
  }

  float* out = &partH[((size_t)bl * NS + ns) * 1024];
#pragma unroll
  for (int r = 0; r < 4; ++r)
    out[(wm + qd * 4 + r) * 32 + (wn + md)] = acc[r];
}

// ---------------- reduce partials + Cholesky logdet ----------------
__global__ __launch_bounds__(256) void k_gram2(
    const float* __restrict__ partH,
    const float* __restrict__ w0p, const float* __restrict__ w1p,
    float* __restrict__ outLD, int b0)
{
  const int bl = blockIdx.x, b = b0 + bl, tid = threadIdx.x;
  __shared__ float sH[32][33];
  __shared__ float sred[32];
  const float spw0 = sp_f(w0p[0]);
  const float spw1 = sp_f(w1p[0]);
  const float* base = &partH[(size_t)bl * NS * 1024];
#pragma unroll
  for (int r = 0; r < 4; ++r) {
    const int e = r * 256 + tid;
    float s = 0.f;
#pragma unroll
    for (int ns = 0; ns < NS; ++ns) s += base[ns * 1024 + e];
    float h = s * spw1;
    const int row = e >> 5, col = e & 31;
    if (row == col) h += spw0;
    sH[row][col] = h;
  }
  __syncthreads();

  float ldacc = 0.f;
  for (int c = 0; c < 32; ++c) {
    if (tid >= c && tid < 32) {
      float s = sH[tid][c];
      for (int m = 0; m < c; ++m) s -= sH[tid][m] * sH[c][m];
      sred[tid] = s;
    }
    __syncthreads();
    const float sc = sred[c];
    if (tid >= c && tid < 32) {
      const float lcc = sqrtf(sc);
      sH[tid][c] = (tid == c) ? lcc : sred[tid] / lcc;
    }
    ldacc += logf(sc);
    __syncthreads();
  }
  if (tid == 0) outLD[b] = ldacc;
}

// ---------------- launcher ----------------
extern "C" void kernel_launch(void* const* d_in, const int* in_sizes, int n_in,
                              void* d_out, int out_size, void* d_ws, size_t ws_size,
                              hipStream_t stream)
{
  const float* X    = (const float*)d_in[0];
  const float* Cc   = (const float*)d_in[1];
  const float* w0   = (const float*)d_in[2];
  const float* w1   = (const float*)d_in[3];
  const float* Wz0w = (const float*)d_in[4];
  const float* Wz0b = (const float*)d_in[5];
  const float* Wc0w = (const float*)d_in[6];
  const float* Wc0b = (const float*)d_in[7];
  const float* an0b = (const float*)d_in[8];
  const float* an0l = (const float*)d_in[9];
  const float* Wz1w = (const float*)d_in[10];
  const float* Wz1b = (const float*)d_in[11];
  const float* Wx1w = (const float*)d_in[12];
  const float* Wx1b = (const float*)d_in[13];
  const float* Wc1w = (const float*)d_in[14];
  const float* Wc1b = (const float*)d_in[15];
  const float* an1b = (const float*)d_in[16];
  const float* an1l = (const float*)d_in[17];
  const float* Wz2w = (const float*)d_in[18];
  const float* Wz2b = (const float*)d_in[19];
  const float* Wx2w = (const float*)d_in[20];
  const float* Wx2b = (const float*)d_in[21];
  const float* Wc2w = (const float*)d_in[22];
  const float* Wc2b = (const float*)d_in[23];
  const float* an2b = (const float*)d_in[24];
  const float* an2l = (const float*)d_in[25];
  const float* Wzoutw = (const float*)d_in[26];
  const float* Wxoutw = (const float*)d_in[27];
  // d_in[28] (Wcout_w): constant in x -> no grad/Hessian contribution.

  float* ws = (float*)d_ws;
  size_t off = 0;
  auto alloc = [&](size_t n) {
    float* p = ws + off; off += (n + 3) & ~(size_t)3; return p;
  };
  const size_t HH = (size_t)NH * NH;
  const size_t BH = (size_t)NB * NH;

  short* S1b  = (short*)alloc(HH / 2);
  short* S2b  = (short*)alloc(HH / 2);
  short* S1Tb = (short*)alloc(HH / 2);
  short* S2Tb = (short*)alloc(HH / 2);
  short* Wc0bb = (short*)alloc((size_t)NH * NC / 2);
  short* Wc1bb = (short*)alloc((size_t)NH * NC / 2);
  short* Wc2bb = (short*)alloc((size_t)NH * NC / 2);
  short* Ccb  = (short*)alloc((size_t)NB * NC / 2);
  short* W0Tb = (short*)alloc((size_t)NDIM * NH / 2);
  float* so   = alloc(NH);
  float* HP   = alloc(BH);
  short* Z0b  = (short*)alloc(BH / 2);
  short* Z1b  = (short*)alloc(BH / 2);
  float* G0   = alloc(BH);
  float* U0   = alloc(BH);
  float* G1   = alloc(BH);
  float* U1   = alloc(BH);
  float* D2u  = alloc(BH);
  short* D2gb = (short*)alloc(BH / 2);
  float* T1   = alloc(BH);
  short* E1b  = (short*)alloc(BH / 2);
  float* D1   = alloc(BH);
  float* T0   = alloc(BH);
  float* D0   = alloc(BH);
  short* GT0b = (short*)alloc(BH / 2);

  // chunk buffers: Ah1, A2, Q1, Q2 (bf16) + partH (fp32)
  const size_t avail_f = ws_size / sizeof(float);
  int CB = 32;
  const int cands[5] = {512, 256, 128, 64, 32};
  for (int ci = 0; ci < 5; ++ci) {
    const size_t need = off + 4 * ((size_t)cands[ci] * 32 * NH / 2 + 4)
                      + (size_t)cands[ci] * NS * 1024 + 64;
    if (need <= avail_f) { CB = cands[ci]; break; }
  }
  const size_t chunk_sh = (size_t)CB * 32 * NH;   // shorts per bf16 buffer
  short* Ah1 = (short*)alloc(chunk_sh / 2);
  short* A2b = (short*)alloc(chunk_sh / 2);
  short* Q1b = (short*)alloc(chunk_sh / 2);
  short* Q2b = (short*)alloc(chunk_sh / 2);
  float* partH = alloc((size_t)CB * NS * 1024);

  float* outF  = (float*)d_out;
  float* outLD = (float*)d_out + NB * NDIM;

  const dim3 blk2(16, 16);
  const dim3 gridX(16, NB / 64);          // fp32 gemm, K=32 terms
  const dim3 gridE(NB * NH / 256);
  const dim3 grid64(NH / 64, NB / 64);    // 64-tile mfma, M=N=1024 -> 256 blocks
  const float invH = 1.0f / (float)NH;

  k_prep<<<dim3(HH / 256), dim3(256), 0, stream>>>(
      Wz1w, Wz2w, Wzoutw, Wz0w, Wc0w, Wc1w, Wc2w, Cc,
      S1b, S1Tb, S2b, S2Tb, Wc0bb, Wc1bb, Wc2bb, Ccb, W0Tb, so);

  // layer 0: HP = X@Wz0^T + Cc@Wc0^T
  k_gemm<0><<<gridX, blk2, 0, stream>>>(X, Wz0w, HP, NDIM, NDIM, 1.f);
  k_mgemm64<3><<<grid64, dim3(256), 0, stream>>>(Ccb, Wc0bb, HP, 1.f, NC);
  k_act<<<gridE, dim3(256), 0, stream>>>(HP, Wz0b, Wc0b, nullptr, an0b, an0l, Z0b, G0, U0, 0);
  // layer 1: HP = Z0@S1^T/H + X@Wx1^T + Cc@Wc1^T
  k_mgemm64<0><<<grid64, dim3(256), 0, stream>>>(Z0b, S1b, HP, invH, NH);
  k_gemm<1><<<gridX, blk2, 0, stream>>>(X, Wx1w, HP, NDIM, NDIM, 1.f);
  k_mgemm64<3><<<grid64, dim3(256), 0, stream>>>(Ccb, Wc1bb, HP, 1.f, NC);
  k_act<<<gridE, dim3(256), 0, stream>>>(HP, Wz1b, Wx1b, Wc1b, an1b, an1l, Z1b, G1, U1, 1);
  // layer 2
  k_mgemm64<0><<<grid64, dim3(256), 0, stream>>>(Z1b, S2b, HP, invH, NH);
  k_gemm<1><<<gridX, blk2, 0, stream>>>(X, Wx2w, HP, NDIM, NDIM, 1.f);
  k_mgemm64<3><<<grid64, dim3(256), 0, stream>>>(Ccb, Wc2bb, HP, 1.f, NC);
  k_act2<<<gridE, dim3(256), 0, stream>>>(HP, Wz2b, Wx2b, Wc2b, an2b, an2l, so, D2u, D2gb);
  // backward sensitivities
  k_mgemm64<0><<<grid64, dim3(256), 0, stream>>>(D2gb, S2Tb, T1, invH, NH);
  k_bw1<<<gridE, dim3(256), 0, stream>>>(T1, G1, U1, E1b, D1);
  k_mgemm64<0><<<grid64, dim3(256), 0, stream>>>(E1b, S1Tb, T0, invH, NH);
  k_bw0<<<gridE, dim3(256), 0, stream>>>(T0, U0, G0, D0, GT0b);

  // f (grad) via backprop identity — whole batch, one kernel
  k_fvec<<<dim3(NB / 4), dim3(128), 0, stream>>>(
      GT0b, E1b, D2gb, Wz0w, Wx1w, Wx2w, X, Wxoutw, w0, w1, outF);

  // Jacobian propagation + K-split Gram + Cholesky, chunked over samples
  const dim3 gridJ(NH / 128, CB * 32 / 128);
  const dim3 gridS((size_t)CB * 32 * NH / 256);
  const dim3 gridG(NS, CB);
  for (int b0 = 0; b0 < NB; b0 += CB) {
    k_scale0<<<gridS, dim3(256), 0, stream>>>(G0, Wz0w, Ah1, b0);
    k_mgemm<2><<<gridJ, dim3(256), 0, stream>>>(Ah1, S1b, Q1b, A2b,
                                                G1, D1, Wx1w, invH, NH, b0);
    k_mgemm<1><<<gridJ, dim3(256), 0, stream>>>(A2b, S2b, Q2b, nullptr,
                                                nullptr, D2u, Wx2w, invH, NH, b0);
    k_gram<<<gridG, dim3(256), 0, stream>>>(Q1b, Q2b, W0Tb, D0, partH, b0);
    k_gram2<<<dim3(CB), dim3(256), 0, stream>>>(partH, w0, w1, outLD, b0);
  }
}

// Round 5
// 818.125 us; speedup vs baseline: 3.1693x; 1.1187x over previous
//
#include <hip/hip_runtime.h>

constexpr int NB   = 1024;  // batch
constexpr int NDIM = 32;    // x dim
constexpr int NH   = 1024;  // hidden dim
constexpr int NC   = 512;   // context dim
constexpr int NS   = 8;     // K-splits in k_gram
constexpr int KSF  = 8;     // K-splits per term in k_fgemm

constexpr float INV_SQRT2PI = 0.3989422804014327f;
constexpr float SQRT_HALF   = 0.70710678118654752f;
constexpr float SQRT_HPI    = 1.2533141373155003f;

typedef __attribute__((ext_vector_type(8))) short short8;
typedef __attribute__((ext_vector_type(4))) float float4v;

__device__ __forceinline__ float sp_f(float x) {
  return (x > 20.f) ? x : log1pf(expf(x));
}

__device__ __forceinline__ short f2bf(float f) {
  union { float f; unsigned u; } x; x.f = f;
  const unsigned r = x.u + 0x7fffu + ((x.u >> 16) & 1u);
  return (short)(r >> 16);
}

__device__ __forceinline__ float bf2f(short s) {
  union { unsigned u; float f; } c;
  c.u = ((unsigned)(unsigned short)s) << 16;
  return c.f;
}

__device__ __forceinline__ void async_ld16(const void* g, void* l) {
  __builtin_amdgcn_global_load_lds(
      (const __attribute__((address_space(1))) void*)g,
      (__attribute__((address_space(3))) void*)l, 16, 0, 0);
}

// ---------------- prep: softplus(Wz1/Wz2/Wzout)->bf16, Wc*->bf16, Cc->bf16, W^T->bf16 ----------------
__global__ __launch_bounds__(256) void k_prep(
    const float* __restrict__ Wz1, const float* __restrict__ Wz2,
    const float* __restrict__ Wzout, const float* __restrict__ Wz0,
    const float* __restrict__ Wx1, const float* __restrict__ Wx2,
    const float* __restrict__ Wc0, const float* __restrict__ Wc1,
    const float* __restrict__ Wc2, const float* __restrict__ Cc,
    short* __restrict__ S1b, short* __restrict__ S1Tb,
    short* __restrict__ S2b, short* __restrict__ S2Tb,
    short* __restrict__ Wc0b, short* __restrict__ Wc1b, short* __restrict__ Wc2b,
    short* __restrict__ Ccb, short* __restrict__ W0Tb,
    short* __restrict__ Wx1Tb, short* __restrict__ Wx2Tb,
    float* __restrict__ so)
{
  const int idx = blockIdx.x * 256 + threadIdx.x;   // 0 .. NH*NH-1
  const int i = idx >> 10, p = idx & 1023;
  const float v1 = sp_f(Wz1[idx]);
  const short b1 = f2bf(v1);
  S1b[idx] = b1; S1Tb[p * NH + i] = b1;
  const float v2 = sp_f(Wz2[idx]);
  const short b2 = f2bf(v2);
  S2b[idx] = b2; S2Tb[p * NH + i] = b2;
  if (idx < NH) so[idx] = sp_f(Wzout[idx]);
  if (idx < NH * NC) {
    Wc0b[idx] = f2bf(Wc0[idx]);
    Wc1b[idx] = f2bf(Wc1[idx]);
    Wc2b[idx] = f2bf(Wc2[idx]);
  }
  if (idx < NB * NC) Ccb[idx] = f2bf(Cc[idx]);
  if (idx < NDIM * NH) {
    const int j = idx >> 10, pp = idx & 1023;   // out [32,1024]
    W0Tb[idx]  = f2bf(Wz0[pp * NDIM + j]);
    Wx1Tb[idx] = f2bf(Wx1[pp * NDIM + j]);
    Wx2Tb[idx] = f2bf(Wx2[pp * NDIM + j]);
  }
}

// ---------------- fp32 tiled GEMM (K=32 X-terms only) ----------------
template<int EPI>  // 0: C=acc, 1: C+=acc
__global__ __launch_bounds__(256) void k_gemm(
    const float* __restrict__ A, const float* __restrict__ Bt,
    float* __restrict__ C, int K, int lda, float scale)
{
  __shared__ float As[16][68];
  __shared__ float Bs[16][68];
  const int tid  = threadIdx.y * 16 + threadIdx.x;
  const int arow = tid >> 2;
  const int acol = (tid & 3) << 2;
  const int m0 = blockIdx.y << 6;
  const int n0 = blockIdx.x << 6;

  float acc[4][4];
#pragma unroll
  for (int i = 0; i < 4; ++i)
#pragma unroll
    for (int j = 0; j < 4; ++j) acc[i][j] = 0.f;

  const int R = m0 + arow;
  for (int k0 = 0; k0 < K; k0 += 16) {
    const float4 av = *reinterpret_cast<const float4*>(&A[(size_t)R * lda + k0 + acol]);
    As[acol + 0][arow] = av.x; As[acol + 1][arow] = av.y;
    As[acol + 2][arow] = av.z; As[acol + 3][arow] = av.w;
    const float4 bv = *reinterpret_cast<const float4*>(&Bt[(size_t)(n0 + arow) * K + k0 + acol]);
    Bs[acol + 0][arow] = bv.x; Bs[acol + 1][arow] = bv.y;
    Bs[acol + 2][arow] = bv.z; Bs[acol + 3][arow] = bv.w;
    __syncthreads();
#pragma unroll
    for (int kk = 0; kk < 16; ++kk) {
      const float4 a  = *reinterpret_cast<const float4*>(&As[kk][threadIdx.y << 2]);
      const float4 bb = *reinterpret_cast<const float4*>(&Bs[kk][threadIdx.x << 2]);
      const float am[4] = {a.x, a.y, a.z, a.w};
      const float bn[4] = {bb.x, bb.y, bb.z, bb.w};
#pragma unroll
      for (int i2 = 0; i2 < 4; ++i2)
#pragma unroll
        for (int j2 = 0; j2 < 4; ++j2)
          acc[i2][j2] = fmaf(am[i2], bn[j2], acc[i2][j2]);
    }
    __syncthreads();
  }
#pragma unroll
  for (int i2 = 0; i2 < 4; ++i2) {
    const int row = m0 + (threadIdx.y << 2) + i2;
    const int col = n0 + (threadIdx.x << 2);
    float* cp = &C[(size_t)row * NH + col];
    float4 o;
    o.x = acc[i2][0] * scale; o.y = acc[i2][1] * scale;
    o.z = acc[i2][2] * scale; o.w = acc[i2][3] * scale;
    if constexpr (EPI == 1) {
      const float4 cur = *reinterpret_cast<const float4*>(cp);
      o.x += cur.x; o.y += cur.y; o.z += cur.z; o.w += cur.w;
    }
    *reinterpret_cast<float4*>(cp) = o;
  }
}

// ---------------- bf16 MFMA GEMM, 128x128 tile, fp32 C with arbitrary ldc ----------------
// C[rowg*ldc + colg] = scale * (A[M,K] @ Bt[N,K]^T)     (c-path fused GEMM)
__global__ __launch_bounds__(256) void k_m128(
    const short* __restrict__ A, const short* __restrict__ Bt,
    float* __restrict__ C, float scale, int K, int ldc)
{
  __shared__ short As[128 * 32];
  __shared__ short Bs[128 * 32];
  const int tid  = threadIdx.x;
  const int wave = tid >> 6, lane = tid & 63;
  const int m0 = blockIdx.y << 7, n0 = blockIdx.x << 7;
  const int wm = (wave >> 1) << 6, wn = (wave & 1) << 6;
  const int qd = lane >> 4, md = lane & 15;
  const int sr = lane >> 2;
  const int sc = (lane & 3) << 3;

  float4v acc[4][4];
#pragma unroll
  for (int i = 0; i < 4; ++i)
#pragma unroll
    for (int j = 0; j < 4; ++j) acc[i][j] = (float4v)(0.f);

  for (int k0 = 0; k0 < K; k0 += 32) {
#pragma unroll
    for (int i = 0; i < 2; ++i) {
      const int ch  = wave * 2 + i;
      const int row = ch * 16 + sr;
      async_ld16(&A [(size_t)(m0 + row) * K + k0 + sc], &As[ch * 512]);
      async_ld16(&Bt[(size_t)(n0 + row) * K + k0 + sc], &Bs[ch * 512]);
    }
    __syncthreads();
    short8 af[4], bfr[4];
#pragma unroll
    for (int t = 0; t < 4; ++t) {
      af[t]  = *(const short8*)&As[(wm + t * 16 + md) * 32 + qd * 8];
      bfr[t] = *(const short8*)&Bs[(wn + t * 16 + md) * 32 + qd * 8];
    }
#pragma unroll
    for (int i = 0; i < 4; ++i)
#pragma unroll
      for (int j = 0; j < 4; ++j)
        acc[i][j] = __builtin_amdgcn_mfma_f32_16x16x32_bf16(af[i], bfr[j], acc[i][j], 0, 0, 0);
    __syncthreads();
  }

#pragma unroll
  for (int i = 0; i < 4; ++i) {
#pragma unroll
    for (int j = 0; j < 4; ++j) {
      const int colg = n0 + wn + j * 16 + md;
#pragma unroll
      for (int r = 0; r < 4; ++r) {
        const int rowg = m0 + wm + i * 16 + qd * 4 + r;
        C[(size_t)rowg * ldc + colg] = acc[i][j][r] * scale;
      }
    }
  }
}

// ---------------- bf16 MFMA GEMM, 128x128 tile (Jacobian GEMMs) ----------------
// EPI 1: (GEMM2) m = acc*scale + wepi;  o1 = bf16(m * sqrt(dvec))            [Q2]
// EPI 2: (GEMM1) m = acc*scale + wepi;  o1 = bf16(m * sqrt(dvec)), o2 = bf16(m * gvec)  [Q1, A2]
template<int EPI>
__global__ __launch_bounds__(256) void k_mgemm(
    const short* __restrict__ A, const short* __restrict__ Bt,
    short* __restrict__ o1, short* __restrict__ o2,
    const float* __restrict__ gvec, const float* __restrict__ dvec,
    const float* __restrict__ wepi,
    float scale, int K, int b0)
{
  __shared__ short As[128 * 32];
  __shared__ short Bs[128 * 32];
  const int tid  = threadIdx.x;
  const int wave = tid >> 6, lane = tid & 63;
  const int m0 = blockIdx.y << 7, n0 = blockIdx.x << 7;
  const int wm = (wave >> 1) << 6, wn = (wave & 1) << 6;
  const int qd = lane >> 4, md = lane & 15;

  float4v acc[4][4];
#pragma unroll
  for (int i = 0; i < 4; ++i)
#pragma unroll
    for (int j = 0; j < 4; ++j) acc[i][j] = (float4v)(0.f);

  const int sr = lane >> 2;
  const int sc = (lane & 3) << 3;

  for (int k0 = 0; k0 < K; k0 += 32) {
#pragma unroll
    for (int i = 0; i < 2; ++i) {
      const int ch  = wave * 2 + i;
      const int row = ch * 16 + sr;
      async_ld16(&A [(size_t)(m0 + row) * K + k0 + sc], &As[ch * 512]);
      async_ld16(&Bt[(size_t)(n0 + row) * K + k0 + sc], &Bs[ch * 512]);
    }
    __syncthreads();
    short8 af[4], bfr[4];
#pragma unroll
    for (int t = 0; t < 4; ++t) {
      af[t]  = *(const short8*)&As[(wm + t * 16 + md) * 32 + qd * 8];
      bfr[t] = *(const short8*)&Bs[(wn + t * 16 + md) * 32 + qd * 8];
    }
#pragma unroll
    for (int i = 0; i < 4; ++i)
#pragma unroll
      for (int j = 0; j < 4; ++j)
        acc[i][j] = __builtin_amdgcn_mfma_f32_16x16x32_bf16(af[i], bfr[j], acc[i][j], 0, 0, 0);
    __syncthreads();
  }

#pragma unroll
  for (int i = 0; i < 4; ++i) {
#pragma unroll
    for (int j = 0; j < 4; ++j) {
      const int colg = n0 + wn + j * 16 + md;
#pragma unroll
      for (int r = 0; r < 4; ++r) {
        const int rowg = m0 + wm + i * 16 + qd * 4 + r;
        const int b = b0 + (rowg >> 5);
        float v = acc[i][j][r] * scale + wepi[colg * NDIM + (rowg & 31)];
        const size_t ci = (size_t)rowg * NH + colg;
        const float dq = sqrtf(fmaxf(dvec[(size_t)b * NH + colg], 0.f));
        o1[ci] = f2bf(v * dq);
        if constexpr (EPI == 2)
          o2[ci] = f2bf(v * gvec[(size_t)b * NH + colg]);
      }
    }
  }
}

// ---------------- bf16 MFMA GEMM, 64x64 tile (fwd/bwd, M=N=1024) ----------------
__global__ __launch_bounds__(256) void k_mgemm64(
    const short* __restrict__ A, const short* __restrict__ Bt,
    float* __restrict__ C, float scale, int K)
{
  __shared__ short As[64 * 32];
  __shared__ short Bs[64 * 32];
  const int tid  = threadIdx.x;
  const int wave = tid >> 6, lane = tid & 63;
  const int m0 = blockIdx.y << 6, n0 = blockIdx.x << 6;
  const int wm = (wave >> 1) << 5, wn = (wave & 1) << 5;
  const int qd = lane >> 4, md = lane & 15;
  const int sr = lane >> 2;
  const int sc = (lane & 3) << 3;

  float4v acc[2][2];
#pragma unroll
  for (int i = 0; i < 2; ++i)
#pragma unroll
    for (int j = 0; j < 2; ++j) acc[i][j] = (float4v)(0.f);

  for (int k0 = 0; k0 < K; k0 += 32) {
    const int row = wave * 16 + sr;
    async_ld16(&A [(size_t)(m0 + row) * K + k0 + sc], &As[wave * 512]);
    async_ld16(&Bt[(size_t)(n0 + row) * K + k0 + sc], &Bs[wave * 512]);
    __syncthreads();
    short8 af[2], bfr[2];
#pragma unroll
    for (int t = 0; t < 2; ++t) {
      af[t]  = *(const short8*)&As[(wm + t * 16 + md) * 32 + qd * 8];
      bfr[t] = *(const short8*)&Bs[(wn + t * 16 + md) * 32 + qd * 8];
    }
#pragma unroll
    for (int i = 0; i < 2; ++i)
#pragma unroll
      for (int j = 0; j < 2; ++j)
        acc[i][j] = __builtin_amdgcn_mfma_f32_16x16x32_bf16(af[i], bfr[j], acc[i][j], 0, 0, 0);
    __syncthreads();
  }

#pragma unroll
  for (int i = 0; i < 2; ++i) {
#pragma unroll
    for (int j = 0; j < 2; ++j) {
      const int colg = n0 + wn + j * 16 + md;
#pragma unroll
      for (int r = 0; r < 4; ++r) {
        const int rowg = m0 + wm + i * 16 + qd * 4 + r;
        C[(size_t)rowg * NH + colg] = acc[i][j][r] * scale;
      }
    }
  }
}

// ---------------- activation (layers 0/1): writes Zbf (bf16), G, U ----------------
// HPC_l points at the layer's slice of the fused c-GEMM output (row stride 3*NH)
__global__ __launch_bounds__(256) void k_act(
    const float* __restrict__ HP, const float* __restrict__ HPC_l,
    const float* __restrict__ bA, const float* __restrict__ bB,
    const float* __restrict__ bC,
    const float* __restrict__ anb, const float* __restrict__ anl,
    short* __restrict__ Zbf, float* __restrict__ G, float* __restrict__ U,
    int hasC)
{
  const int idx = blockIdx.x * 256 + threadIdx.x;
  const int i = idx & 1023;
  float bias = bA[i] + bB[i] + anb[i];
  if (hasC) bias += bC[i];
  const float el = expf(anl[i]);
  const float hc = HPC_l[(size_t)(idx >> 10) * (3 * NH) + i];
  const float a = (HP[idx] + hc + bias) * el;
  const float pdf = expf(-0.5f * a * a);
  const float er = erff(a * SQRT_HALF);
  Zbf[idx] = f2bf((SQRT_HPI * a * er + pdf + SQRT_HPI * a) * INV_SQRT2PI);
  G[idx] = 0.5f * (1.f + er) * el;
  U[idx] = pdf * INV_SQRT2PI * el * el;
}

// ---------------- activation (layer 2): D2u fp32, D2g bf16 ----------------
__global__ __launch_bounds__(256) void k_act2(
    const float* __restrict__ HP, const float* __restrict__ HPC_l,
    const float* __restrict__ bA, const float* __restrict__ bB,
    const float* __restrict__ bC,
    const float* __restrict__ anb, const float* __restrict__ anl,
    const float* __restrict__ so,
    float* __restrict__ D2u, short* __restrict__ D2gbf)
{
  const int idx = blockIdx.x * 256 + threadIdx.x;
  const int i = idx & 1023;
  const float bias = bA[i] + bB[i] + bC[i] + anb[i];
  const float el = expf(anl[i]);
  const float hc = HPC_l[(size_t)(idx >> 10) * (3 * NH) + i];
  const float a = (HP[idx] + hc + bias) * el;
  const float pdf = expf(-0.5f * a * a);
  const float er = erff(a * SQRT_HALF);
  const float g = 0.5f * (1.f + er) * el;
  const float u = pdf * INV_SQRT2PI * el * el;
  const float t2 = so[i] * (1.f / NH);
  D2u[idx] = t2 * u;
  D2gbf[idx] = f2bf(t2 * g);
}

__global__ __launch_bounds__(256) void k_bw1(
    const float* __restrict__ T1, const float* __restrict__ G1,
    const float* __restrict__ U1,
    short* __restrict__ E1bf, float* __restrict__ D1)
{
  const int idx = blockIdx.x * 256 + threadIdx.x;
  const float t = T1[idx];
  E1bf[idx] = f2bf(t * G1[idx]);
  D1[idx] = t * U1[idx];
}

// D0 = T0*U0 (fp32), GT0b = bf16(T0*G0)
__global__ __launch_bounds__(256) void k_bw0(
    const float* __restrict__ T0, const float* __restrict__ U0,
    const float* __restrict__ G0,
    float* __restrict__ D0, short* __restrict__ GT0b)
{
  const int idx = blockIdx.x * 256 + threadIdx.x;
  const float t = T0[idx];
  D0[idx] = t * U0[idx];
  GT0b[idx] = f2bf(t * G0[idx]);
}

// ---------------- Ah1[r,p] = bf16(G0[b,p] * Wz0[p, r&31]) ----------------
__global__ __launch_bounds__(256) void k_scale0(
    const float* __restrict__ G0, const float* __restrict__ Wz0,
    short* __restrict__ Ah1, int b0)
{
  const int idx = blockIdx.x * 256 + threadIdx.x;
  const int p = idx & 1023, r = idx >> 10;
  const int b = b0 + (r >> 5), j = r & 31;
  Ah1[idx] = f2bf(G0[(size_t)b * NH + p] * Wz0[p * NDIM + j]);
}

// ---------------- f-GEMM: MFMA partials of [NB,NH]@[NH,32] per term/k-split ----------------
__global__ __launch_bounds__(256) void k_fgemm(
    const short* __restrict__ A0, const short* __restrict__ A1,
    const short* __restrict__ A2,
    const short* __restrict__ W0T, const short* __restrict__ W1T,
    const short* __restrict__ W2T,
    float* __restrict__ partF)
{
  const int mb = blockIdx.x;          // 0..7 (128 samples)
  const int ks = blockIdx.y;          // 0..KSF-1
  const int term = blockIdx.z;        // 0..2
  const short* A  = (term == 0) ? A0 : (term == 1) ? A1 : A2;
  const short* WT = (term == 0) ? W0T : (term == 1) ? W1T : W2T;
  const int wave = threadIdx.x >> 6, lane = threadIdx.x & 63;
  const int qd = lane >> 4, md = lane & 15;
  const int m0 = mb * 128 + wave * 32;
  const int kbeg = ks * (NH / KSF);   // 128-wide slice

  float4v acc[2][2];
#pragma unroll
  for (int i = 0; i < 2; ++i)
#pragma unroll
    for (int j = 0; j < 2; ++j) acc[i][j] = (float4v)(0.f);

  for (int k0 = kbeg; k0 < kbeg + NH / KSF; k0 += 32) {
    const int kk = k0 + qd * 8;
    short8 af[2], bfr[2];
    af[0]  = *(const short8*)&A[(size_t)(m0 + md) * NH + kk];
    af[1]  = *(const short8*)&A[(size_t)(m0 + 16 + md) * NH + kk];
    bfr[0] = *(const short8*)&WT[(size_t)md * NH + kk];
    bfr[1] = *(const short8*)&WT[(size_t)(16 + md) * NH + kk];
#pragma unroll
    for (int i = 0; i < 2; ++i)
#pragma unroll
      for (int j = 0; j < 2; ++j)
        acc[i][j] = __builtin_amdgcn_mfma_f32_16x16x32_bf16(af[i], bfr[j], acc[i][j], 0, 0, 0);
  }

  float* out = &partF[(size_t)(term * KSF + ks) * NB * 32];
#pragma unroll
  for (int i = 0; i < 2; ++i)
#pragma unroll
    for (int j = 0; j < 2; ++j)
#pragma unroll
      for (int r = 0; r < 4; ++r) {
        const int row = m0 + i * 16 + qd * 4 + r;
        const int col = j * 16 + md;
        out[(size_t)row * 32 + col] = acc[i][j][r];
      }
}

// ---------------- reduce f partials + epilogue ----------------
__global__ __launch_bounds__(256) void k_fred(
    const float* __restrict__ partF, const float* __restrict__ X,
    const float* __restrict__ Wxout,
    const float* __restrict__ w0p, const float* __restrict__ w1p,
    float* __restrict__ outF)
{
  const int e = blockIdx.x * 256 + threadIdx.x;   // 0 .. NB*32-1
  float s = 0.f;
#pragma unroll
  for (int p = 0; p < 3 * KSF; ++p) s += partF[(size_t)p * NB * 32 + e];
  const float spw0 = sp_f(w0p[0]);
  const float spw1 = sp_f(w1p[0]);
  outF[e] = spw1 * (s + Wxout[e & 31]) + spw0 * X[e];
}

// ---------------- K-split per-sample Gram partials (no LDS, no barriers) ----------------
__global__ __launch_bounds__(256) void k_gram(
    const short* __restrict__ Q1, const short* __restrict__ Q2,
    const short* __restrict__ W0T, const float* __restrict__ D0,
    float* __restrict__ partH, int b0)
{
  const int ns = blockIdx.x, bl = blockIdx.y;
  const int b = b0 + bl;
  const int wave = threadIdx.x >> 6, lane = threadIdx.x & 63;
  const int wm = (wave >> 1) << 4, wn = (wave & 1) << 4;
  const int qd = lane >> 4, md = lane & 15;
  const int kbeg = ns << 7;           // ns * 128
  const size_t rb = (size_t)bl * 32 * NH;

  float4v acc = (float4v)(0.f);

  // layer 0: Gram0 = W0^T diag(D0) W0  (scale A-side by D0 in registers)
  for (int k0 = kbeg; k0 < kbeg + 128; k0 += 32) {
    const int kk = k0 + qd * 8;
    const short8 ar = *(const short8*)&W0T[(size_t)(wm + md) * NH + kk];
    float dd[8];
    *(float4*)&dd[0] = *(const float4*)&D0[(size_t)b * NH + kk];
    *(float4*)&dd[4] = *(const float4*)&D0[(size_t)b * NH + kk + 4];
    short8 af;
#pragma unroll
    for (int e = 0; e < 8; ++e) af[e] = f2bf(bf2f(ar[e]) * dd[e]);
    const short8 bfr = *(const short8*)&W0T[(size_t)(wn + md) * NH + kk];
    acc = __builtin_amdgcn_mfma_f32_16x16x32_bf16(af, bfr, acc, 0, 0, 0);
  }
  // layers 1,2: Gram = Q Q^T (Q pre-scaled by sqrt(D))
#pragma unroll
  for (int l = 0; l < 2; ++l) {
    const short* Q = (l == 0) ? Q1 : Q2;
    for (int k0 = kbeg; k0 < kbeg + 128; k0 += 32) {
      const int kk = k0 + qd * 8;
      const short8 af  = *(const short8*)&Q[rb + (size_t)(wm + md) * NH + kk];
      const short8 bfr = *(const short8*)&Q[rb + (size_t)(wn + md) * NH + kk];
      acc = __builtin_amdgcn_mfma_f32_16x16x32_bf16(af, bfr, acc, 0, 0, 0);
    }
  }

  float* out = &partH[((size_t)bl * NS + ns) * 1024];
#pragma unroll
  for (int r = 0; r < 4; ++r)
    out[(wm + qd * 4 + r) * 32 + (wn + md)] = acc[r];
}

// ---------------- reduce partials + Cholesky logdet ----------------
__global__ __launch_bounds__(256) void k_gram2(
    const float* __restrict__ partH,
    const float* __restrict__ w0p, const float* __restrict__ w1p,
    float* __restrict__ outLD, int b0)
{
  const int bl = blockIdx.x, b = b0 + bl, tid = threadIdx.x;
  __shared__ float sH[32][33];
  __shared__ float sred[32];
  const float spw0 = sp_f(w0p[0]);
  const float spw1 = sp_f(w1p[0]);
  const float* base = &partH[(size_t)bl * NS * 1024];
#pragma unroll
  for (int r = 0; r < 4; ++r) {
    const int e = r * 256 + tid;
    float s = 0.f;
#pragma unroll
    for (int ns = 0; ns < NS; ++ns) s += base[ns * 1024 + e];
    float h = s * spw1;
    const int row = e >> 5, col = e & 31;
    if (row == col) h += spw0;
    sH[row][col] = h;
  }
  __syncthreads();

  float ldacc = 0.f;
  for (int c = 0; c < 32; ++c) {
    if (tid >= c && tid < 32) {
      float s = sH[tid][c];
      for (int m = 0; m < c; ++m) s -= sH[tid][m] * sH[c][m];
      sred[tid] = s;
    }
    __syncthreads();
    const float sc = sred[c];
    if (tid >= c && tid < 32) {
      const float lcc = sqrtf(sc);
      sH[tid][c] = (tid == c) ? lcc : sred[tid] / lcc;
    }
    ldacc += logf(sc);
    __syncthreads();
  }
  if (tid == 0) outLD[b] = ldacc;
}

// ---------------- launcher ----------------
extern "C" void kernel_launch(void* const* d_in, const int* in_sizes, int n_in,
                              void* d_out, int out_size, void* d_ws, size_t ws_size,
                              hipStream_t stream)
{
  const float* X    = (const float*)d_in[0];
  const float* Cc   = (const float*)d_in[1];
  const float* w0   = (const float*)d_in[2];
  const float* w1   = (const float*)d_in[3];
  const float* Wz0w = (const float*)d_in[4];
  const float* Wz0b = (const float*)d_in[5];
  const float* Wc0w = (const float*)d_in[6];
  const float* Wc0b = (const float*)d_in[7];
  const float* an0b = (const float*)d_in[8];
  const float* an0l = (const float*)d_in[9];
  const float* Wz1w = (const float*)d_in[10];
  const float* Wz1b = (const float*)d_in[11];
  const float* Wx1w = (const float*)d_in[12];
  const float* Wx1b = (const float*)d_in[13];
  const float* Wc1w = (const float*)d_in[14];
  const float* Wc1b = (const float*)d_in[15];
  const float* an1b = (const float*)d_in[16];
  const float* an1l = (const float*)d_in[17];
  const float* Wz2w = (const float*)d_in[18];
  const float* Wz2b = (const float*)d_in[19];
  const float* Wx2w = (const float*)d_in[20];
  const float* Wx2b = (const float*)d_in[21];
  const float* Wc2w = (const float*)d_in[22];
  const float* Wc2b = (const float*)d_in[23];
  const float* an2b = (const float*)d_in[24];
  const float* an2l = (const float*)d_in[25];
  const float* Wzoutw = (const float*)d_in[26];
  const float* Wxoutw = (const float*)d_in[27];
  // d_in[28] (Wcout_w): constant in x -> no grad/Hessian contribution.

  float* ws = (float*)d_ws;
  size_t off = 0;
  auto alloc = [&](size_t n) {
    float* p = ws + off; off += (n + 3) & ~(size_t)3; return p;
  };
  const size_t HH = (size_t)NH * NH;
  const size_t BH = (size_t)NB * NH;

  short* S1b  = (short*)alloc(HH / 2);
  short* S2b  = (short*)alloc(HH / 2);
  short* S1Tb = (short*)alloc(HH / 2);
  short* S2Tb = (short*)alloc(HH / 2);
  // NOTE: Wc0bb/Wc1bb/Wc2bb must stay contiguous (fused c-GEMM Bt = concat)
  short* Wc0bb = (short*)alloc((size_t)NH * NC / 2);
  short* Wc1bb = (short*)alloc((size_t)NH * NC / 2);
  short* Wc2bb = (short*)alloc((size_t)NH * NC / 2);
  short* Ccb  = (short*)alloc((size_t)NB * NC / 2);
  short* W0Tb = (short*)alloc((size_t)NDIM * NH / 2);
  short* Wx1Tb = (short*)alloc((size_t)NDIM * NH / 2);
  short* Wx2Tb = (short*)alloc((size_t)NDIM * NH / 2);
  float* so   = alloc(NH);
  float* HP   = alloc(BH);
  float* HPC  = alloc((size_t)NB * 3 * NH);   // fused c-path output [NB, 3*NH]
  short* Z0b  = (short*)alloc(BH / 2);
  short* Z1b  = (short*)alloc(BH / 2);
  float* G0   = alloc(BH);
  float* U0   = alloc(BH);
  float* G1   = alloc(BH);
  float* U1   = alloc(BH);
  float* D2u  = alloc(BH);
  short* D2gb = (short*)alloc(BH / 2);
  float* T1   = alloc(BH);
  short* E1b  = (short*)alloc(BH / 2);
  float* D1   = alloc(BH);
  float* T0   = alloc(BH);
  float* D0   = alloc(BH);
  short* GT0b = (short*)alloc(BH / 2);
  float* partF = alloc((size_t)3 * KSF * NB * 32);

  // chunk buffers: Ah1, A2, Q1, Q2 (bf16) + partH (fp32)
  const size_t avail_f = ws_size / sizeof(float);
  int CB = 32;
  const int cands[5] = {512, 256, 128, 64, 32};
  for (int ci = 0; ci < 5; ++ci) {
    const size_t need = off + 4 * ((size_t)cands[ci] * 32 * NH / 2 + 4)
                      + (size_t)cands[ci] * NS * 1024 + 64;
    if (need <= avail_f) { CB = cands[ci]; break; }
  }
  const size_t chunk_sh = (size_t)CB * 32 * NH;   // shorts per bf16 buffer
  short* Ah1 = (short*)alloc(chunk_sh / 2);
  short* A2b = (short*)alloc(chunk_sh / 2);
  short* Q1b = (short*)alloc(chunk_sh / 2);
  short* Q2b = (short*)alloc(chunk_sh / 2);
  float* partH = alloc((size_t)CB * NS * 1024);

  float* outF  = (float*)d_out;
  float* outLD = (float*)d_out + NB * NDIM;

  const dim3 blk2(16, 16);
  const dim3 gridX(16, NB / 64);          // fp32 gemm, K=32 terms
  const dim3 gridE(NB * NH / 256);
  const dim3 grid64(NH / 64, NB / 64);    // 64-tile mfma, M=N=1024
  const dim3 gridC(3 * NH / 128, NB / 128); // fused c-GEMM: N=3072
  const float invH = 1.0f / (float)NH;

  k_prep<<<dim3(HH / 256), dim3(256), 0, stream>>>(
      Wz1w, Wz2w, Wzoutw, Wz0w, Wx1w, Wx2w, Wc0w, Wc1w, Wc2w, Cc,
      S1b, S1Tb, S2b, S2Tb, Wc0bb, Wc1bb, Wc2bb, Ccb, W0Tb, Wx1Tb, Wx2Tb, so);

  // fused c-path: HPC[s, l*NH + i] = (Cc @ Wc_l^T)[s, i], one 128-tile GEMM
  k_m128<<<gridC, dim3(256), 0, stream>>>(Ccb, Wc0bb, HPC, 1.f, NC, 3 * NH);

  // layer 0: a0 = X@Wz0^T + HPC0 (+ biases in k_act)
  k_gemm<0><<<gridX, blk2, 0, stream>>>(X, Wz0w, HP, NDIM, NDIM, 1.f);
  k_act<<<gridE, dim3(256), 0, stream>>>(HP, HPC + 0 * NH, Wz0b, Wc0b, nullptr,
                                         an0b, an0l, Z0b, G0, U0, 0);
  // layer 1
  k_mgemm64<<<grid64, dim3(256), 0, stream>>>(Z0b, S1b, HP, invH, NH);
  k_gemm<1><<<gridX, blk2, 0, stream>>>(X, Wx1w, HP, NDIM, NDIM, 1.f);
  k_act<<<gridE, dim3(256), 0, stream>>>(HP, HPC + 1 * NH, Wz1b, Wx1b, Wc1b,
                                         an1b, an1l, Z1b, G1, U1, 1);
  // layer 2
  k_mgemm64<<<grid64, dim3(256), 0, stream>>>(Z1b, S2b, HP, invH, NH);
  k_gemm<1><<<gridX, blk2, 0, stream>>>(X, Wx2w, HP, NDIM, NDIM, 1.f);
  k_act2<<<gridE, dim3(256), 0, stream>>>(HP, HPC + 2 * NH, Wz2b, Wx2b, Wc2b,
                                          an2b, an2l, so, D2u, D2gb);
  // backward sensitivities
  k_mgemm64<<<grid64, dim3(256), 0, stream>>>(D2gb, S2Tb, T1, invH, NH);
  k_bw1<<<gridE, dim3(256), 0, stream>>>(T1, G1, U1, E1b, D1);
  k_mgemm64<<<grid64, dim3(256), 0, stream>>>(E1b, S1Tb, T0, invH, NH);
  k_bw0<<<gridE, dim3(256), 0, stream>>>(T0, U0, G0, D0, GT0b);

  // f (grad) via MFMA partials + reduce
  k_fgemm<<<dim3(8, KSF, 3), dim3(256), 0, stream>>>(
      GT0b, E1b, D2gb, W0Tb, Wx1Tb, Wx2Tb, partF);
  k_fred<<<dim3(NB * 32 / 256), dim3(256), 0, stream>>>(
      partF, X, Wxoutw, w0, w1, outF);

  // Jacobian propagation + K-split Gram + Cholesky, chunked over samples
  const dim3 gridJ(NH / 128, CB * 32 / 128);
  const dim3 gridS((size_t)CB * 32 * NH / 256);
  const dim3 gridG(NS, CB);
  for (int b0 = 0; b0 < NB; b0 += CB) {
    k_scale0<<<gridS, dim3(256), 0, stream>>>(G0, Wz0w, Ah1, b0);
    k_mgemm<2><<<gridJ, dim3(256), 0, stream>>>(Ah1, S1b, Q1b, A2b,
                                                G1, D1, Wx1w, invH, NH, b0);
    k_mgemm<1><<<gridJ, dim3(256), 0, stream>>>(A2b, S2b, Q2b, nullptr,
                                                nullptr, D2u, Wx2w, invH, NH, b0);
    k_gram<<<gridG, dim3(256), 0, stream>>>(Q1b, Q2b, W0Tb, D0, partH, b0);
    k_gram2<<<dim3(CB), dim3(256), 0, stream>>>(partH, w0, w1, outLD, b0);
  }
}

// Round 6
// 729.257 us; speedup vs baseline: 3.5555x; 1.1219x over previous
//
#include <hip/hip_runtime.h>

constexpr int NB   = 1024;  // batch
constexpr int NDIM = 32;    // x dim
constexpr int NH   = 1024;  // hidden dim
constexpr int NC   = 512;   // context dim
constexpr int NS   = 8;     // K-splits in k_gram
constexpr int KSF  = 8;     // K-splits per term in k_fgemm

constexpr float INV_SQRT2PI = 0.3989422804014327f;
constexpr float SQRT_HALF   = 0.70710678118654752f;
constexpr float SQRT_HPI    = 1.2533141373155003f;

typedef __attribute__((ext_vector_type(8))) short short8;
typedef __attribute__((ext_vector_type(4))) float float4v;

__device__ __forceinline__ float sp_f(float x) {
  return (x > 20.f) ? x : log1pf(expf(x));
}

__device__ __forceinline__ short f2bf(float f) {
  union { float f; unsigned u; } x; x.f = f;
  const unsigned r = x.u + 0x7fffu + ((x.u >> 16) & 1u);
  return (short)(r >> 16);
}

__device__ __forceinline__ float bf2f(short s) {
  union { unsigned u; float f; } c;
  c.u = ((unsigned)(unsigned short)s) << 16;
  return c.f;
}

__device__ __forceinline__ void async_ld16(const void* g, void* l) {
  __builtin_amdgcn_global_load_lds(
      (const __attribute__((address_space(1))) void*)g,
      (__attribute__((address_space(3))) void*)l, 16, 0, 0);
}

// ---------------- prep: softplus(Wz1/Wz2/Wzout)->bf16, Wc*->bf16, Cc->bf16, W^T->bf16 ----------------
__global__ __launch_bounds__(256) void k_prep(
    const float* __restrict__ Wz1, const float* __restrict__ Wz2,
    const float* __restrict__ Wzout, const float* __restrict__ Wz0,
    const float* __restrict__ Wx1, const float* __restrict__ Wx2,
    const float* __restrict__ Wc0, const float* __restrict__ Wc1,
    const float* __restrict__ Wc2, const float* __restrict__ Cc,
    short* __restrict__ S1b, short* __restrict__ S1Tb,
    short* __restrict__ S2b, short* __restrict__ S2Tb,
    short* __restrict__ Wc0b, short* __restrict__ Wc1b, short* __restrict__ Wc2b,
    short* __restrict__ Ccb, short* __restrict__ W0Tb,
    short* __restrict__ Wx1Tb, short* __restrict__ Wx2Tb,
    float* __restrict__ so)
{
  const int idx = blockIdx.x * 256 + threadIdx.x;   // 0 .. NH*NH-1
  const int i = idx >> 10, p = idx & 1023;
  const float v1 = sp_f(Wz1[idx]);
  const short b1 = f2bf(v1);
  S1b[idx] = b1; S1Tb[p * NH + i] = b1;
  const float v2 = sp_f(Wz2[idx]);
  const short b2 = f2bf(v2);
  S2b[idx] = b2; S2Tb[p * NH + i] = b2;
  if (idx < NH) so[idx] = sp_f(Wzout[idx]);
  if (idx < NH * NC) {
    Wc0b[idx] = f2bf(Wc0[idx]);
    Wc1b[idx] = f2bf(Wc1[idx]);
    Wc2b[idx] = f2bf(Wc2[idx]);
  }
  if (idx < NB * NC) Ccb[idx] = f2bf(Cc[idx]);
  if (idx < NDIM * NH) {
    const int j = idx >> 10, pp = idx & 1023;   // out [32,1024]
    W0Tb[idx]  = f2bf(Wz0[pp * NDIM + j]);
    Wx1Tb[idx] = f2bf(Wx1[pp * NDIM + j]);
    Wx2Tb[idx] = f2bf(Wx2[pp * NDIM + j]);
  }
}

// ---------------- fp32 tiled GEMM (K=32 X-terms only) ----------------
template<int EPI>  // 0: C=acc, 1: C+=acc
__global__ __launch_bounds__(256) void k_gemm(
    const float* __restrict__ A, const float* __restrict__ Bt,
    float* __restrict__ C, int K, int lda, float scale)
{
  __shared__ float As[16][68];
  __shared__ float Bs[16][68];
  const int tid  = threadIdx.y * 16 + threadIdx.x;
  const int arow = tid >> 2;
  const int acol = (tid & 3) << 2;
  const int m0 = blockIdx.y << 6;
  const int n0 = blockIdx.x << 6;

  float acc[4][4];
#pragma unroll
  for (int i = 0; i < 4; ++i)
#pragma unroll
    for (int j = 0; j < 4; ++j) acc[i][j] = 0.f;

  const int R = m0 + arow;
  for (int k0 = 0; k0 < K; k0 += 16) {
    const float4 av = *reinterpret_cast<const float4*>(&A[(size_t)R * lda + k0 + acol]);
    As[acol + 0][arow] = av.x; As[acol + 1][arow] = av.y;
    As[acol + 2][arow] = av.z; As[acol + 3][arow] = av.w;
    const float4 bv = *reinterpret_cast<const float4*>(&Bt[(size_t)(n0 + arow) * K + k0 + acol]);
    Bs[acol + 0][arow] = bv.x; Bs[acol + 1][arow] = bv.y;
    Bs[acol + 2][arow] = bv.z; Bs[acol + 3][arow] = bv.w;
    __syncthreads();
#pragma unroll
    for (int kk = 0; kk < 16; ++kk) {
      const float4 a  = *reinterpret_cast<const float4*>(&As[kk][threadIdx.y << 2]);
      const float4 bb = *reinterpret_cast<const float4*>(&Bs[kk][threadIdx.x << 2]);
      const float am[4] = {a.x, a.y, a.z, a.w};
      const float bn[4] = {bb.x, bb.y, bb.z, bb.w};
#pragma unroll
      for (int i2 = 0; i2 < 4; ++i2)
#pragma unroll
        for (int j2 = 0; j2 < 4; ++j2)
          acc[i2][j2] = fmaf(am[i2], bn[j2], acc[i2][j2]);
    }
    __syncthreads();
  }
#pragma unroll
  for (int i2 = 0; i2 < 4; ++i2) {
    const int row = m0 + (threadIdx.y << 2) + i2;
    const int col = n0 + (threadIdx.x << 2);
    float* cp = &C[(size_t)row * NH + col];
    float4 o;
    o.x = acc[i2][0] * scale; o.y = acc[i2][1] * scale;
    o.z = acc[i2][2] * scale; o.w = acc[i2][3] * scale;
    if constexpr (EPI == 1) {
      const float4 cur = *reinterpret_cast<const float4*>(cp);
      o.x += cur.x; o.y += cur.y; o.z += cur.z; o.w += cur.w;
    }
    *reinterpret_cast<float4*>(cp) = o;
  }
}

// ---------------- bf16 MFMA GEMM, 128x128 tile, fp32 C with arbitrary ldc ----------------
// grid: (M/128, N/128) -- blockIdx.x = M-block so same-A blocks share an XCD (bid%8)
__global__ __launch_bounds__(256) void k_m128(
    const short* __restrict__ A, const short* __restrict__ Bt,
    float* __restrict__ C, float scale, int K, int ldc)
{
  __shared__ short As[128 * 32];
  __shared__ short Bs[128 * 32];
  const int tid  = threadIdx.x;
  const int wave = tid >> 6, lane = tid & 63;
  const int m0 = blockIdx.x << 7, n0 = blockIdx.y << 7;   // XCD swizzle
  const int wm = (wave >> 1) << 6, wn = (wave & 1) << 6;
  const int qd = lane >> 4, md = lane & 15;
  const int sr = lane >> 2;
  const int sc = (lane & 3) << 3;

  float4v acc[4][4];
#pragma unroll
  for (int i = 0; i < 4; ++i)
#pragma unroll
    for (int j = 0; j < 4; ++j) acc[i][j] = (float4v)(0.f);

  for (int k0 = 0; k0 < K; k0 += 32) {
#pragma unroll
    for (int i = 0; i < 2; ++i) {
      const int ch  = wave * 2 + i;
      const int row = ch * 16 + sr;
      async_ld16(&A [(size_t)(m0 + row) * K + k0 + sc], &As[ch * 512]);
      async_ld16(&Bt[(size_t)(n0 + row) * K + k0 + sc], &Bs[ch * 512]);
    }
    __syncthreads();
    short8 af[4], bfr[4];
#pragma unroll
    for (int t = 0; t < 4; ++t) {
      af[t]  = *(const short8*)&As[(wm + t * 16 + md) * 32 + qd * 8];
      bfr[t] = *(const short8*)&Bs[(wn + t * 16 + md) * 32 + qd * 8];
    }
#pragma unroll
    for (int i = 0; i < 4; ++i)
#pragma unroll
      for (int j = 0; j < 4; ++j)
        acc[i][j] = __builtin_amdgcn_mfma_f32_16x16x32_bf16(af[i], bfr[j], acc[i][j], 0, 0, 0);
    __syncthreads();
  }

#pragma unroll
  for (int i = 0; i < 4; ++i) {
#pragma unroll
    for (int j = 0; j < 4; ++j) {
      const int colg = n0 + wn + j * 16 + md;
#pragma unroll
      for (int r = 0; r < 4; ++r) {
        const int rowg = m0 + wm + i * 16 + qd * 4 + r;
        C[(size_t)rowg * ldc + colg] = acc[i][j][r] * scale;
      }
    }
  }
}

// ---------------- bf16 MFMA GEMM, 128x128 tile (Jacobian GEMMs) ----------------
// grid: (CB*32/128, NH/128) -- blockIdx.x = M-block (XCD locality on A)
// dvec is PRE-SQRT'd. EPI 1: o1 = bf16(m*dvec)   [Q2]
//                     EPI 2: o1 = bf16(m*dvec), o2 = bf16(m*gvec)   [Q1, A2]
template<int EPI>
__global__ __launch_bounds__(256) void k_mgemm(
    const short* __restrict__ A, const short* __restrict__ Bt,
    short* __restrict__ o1, short* __restrict__ o2,
    const float* __restrict__ gvec, const float* __restrict__ dvec,
    const float* __restrict__ wepi,
    float scale, int K, int b0)
{
  __shared__ short As[128 * 32];
  __shared__ short Bs[128 * 32];
  const int tid  = threadIdx.x;
  const int wave = tid >> 6, lane = tid & 63;
  const int m0 = blockIdx.x << 7, n0 = blockIdx.y << 7;   // XCD swizzle
  const int wm = (wave >> 1) << 6, wn = (wave & 1) << 6;
  const int qd = lane >> 4, md = lane & 15;

  float4v acc[4][4];
#pragma unroll
  for (int i = 0; i < 4; ++i)
#pragma unroll
    for (int j = 0; j < 4; ++j) acc[i][j] = (float4v)(0.f);

  const int sr = lane >> 2;
  const int sc = (lane & 3) << 3;

  for (int k0 = 0; k0 < K; k0 += 32) {
#pragma unroll
    for (int i = 0; i < 2; ++i) {
      const int ch  = wave * 2 + i;
      const int row = ch * 16 + sr;
      async_ld16(&A [(size_t)(m0 + row) * K + k0 + sc], &As[ch * 512]);
      async_ld16(&Bt[(size_t)(n0 + row) * K + k0 + sc], &Bs[ch * 512]);
    }
    __syncthreads();
    short8 af[4], bfr[4];
#pragma unroll
    for (int t = 0; t < 4; ++t) {
      af[t]  = *(const short8*)&As[(wm + t * 16 + md) * 32 + qd * 8];
      bfr[t] = *(const short8*)&Bs[(wn + t * 16 + md) * 32 + qd * 8];
    }
#pragma unroll
    for (int i = 0; i < 4; ++i)
#pragma unroll
      for (int j = 0; j < 4; ++j)
        acc[i][j] = __builtin_amdgcn_mfma_f32_16x16x32_bf16(af[i], bfr[j], acc[i][j], 0, 0, 0);
    __syncthreads();
  }

  // epilogue: hoisted per-column loads; b = b0 + base + (i>>1)
  const int bbase = b0 + ((m0 + wm) >> 5);
#pragma unroll
  for (int j = 0; j < 4; ++j) {
    const int colg = n0 + wn + j * 16 + md;
    const float4 we0 = *(const float4*)&wepi[colg * NDIM + qd * 4];
    const float4 we1 = *(const float4*)&wepi[colg * NDIM + 16 + qd * 4];
    const float dq0 = dvec[(size_t)bbase * NH + colg];
    const float dq1 = dvec[(size_t)(bbase + 1) * NH + colg];
    float gg0 = 0.f, gg1 = 0.f;
    if constexpr (EPI == 2) {
      gg0 = gvec[(size_t)bbase * NH + colg];
      gg1 = gvec[(size_t)(bbase + 1) * NH + colg];
    }
#pragma unroll
    for (int i = 0; i < 4; ++i) {
      const float4 we = (i & 1) ? we1 : we0;
      const float dq = (i >> 1) ? dq1 : dq0;
      const float gg = (i >> 1) ? gg1 : gg0;
      const float wev[4] = {we.x, we.y, we.z, we.w};
#pragma unroll
      for (int r = 0; r < 4; ++r) {
        const int rowg = m0 + wm + i * 16 + qd * 4 + r;
        const float v = acc[i][j][r] * scale + wev[r];
        const size_t ci = (size_t)rowg * NH + colg;
        o1[ci] = f2bf(v * dq);
        if constexpr (EPI == 2) o2[ci] = f2bf(v * gg);
      }
    }
  }
}

// ---------------- bf16 MFMA GEMM, 64x64 tile (fwd/bwd, M=N=1024) ----------------
// grid: (M/64, N/64) -- blockIdx.x = M-block
__global__ __launch_bounds__(256) void k_mgemm64(
    const short* __restrict__ A, const short* __restrict__ Bt,
    float* __restrict__ C, float scale, int K)
{
  __shared__ short As[64 * 32];
  __shared__ short Bs[64 * 32];
  const int tid  = threadIdx.x;
  const int wave = tid >> 6, lane = tid & 63;
  const int m0 = blockIdx.x << 6, n0 = blockIdx.y << 6;   // XCD swizzle
  const int wm = (wave >> 1) << 5, wn = (wave & 1) << 5;
  const int qd = lane >> 4, md = lane & 15;
  const int sr = lane >> 2;
  const int sc = (lane & 3) << 3;

  float4v acc[2][2];
#pragma unroll
  for (int i = 0; i < 2; ++i)
#pragma unroll
    for (int j = 0; j < 2; ++j) acc[i][j] = (float4v)(0.f);

  for (int k0 = 0; k0 < K; k0 += 32) {
    const int row = wave * 16 + sr;
    async_ld16(&A [(size_t)(m0 + row) * K + k0 + sc], &As[wave * 512]);
    async_ld16(&Bt[(size_t)(n0 + row) * K + k0 + sc], &Bs[wave * 512]);
    __syncthreads();
    short8 af[2], bfr[2];
#pragma unroll
    for (int t = 0; t < 2; ++t) {
      af[t]  = *(const short8*)&As[(wm + t * 16 + md) * 32 + qd * 8];
      bfr[t] = *(const short8*)&Bs[(wn + t * 16 + md) * 32 + qd * 8];
    }
#pragma unroll
    for (int i = 0; i < 2; ++i)
#pragma unroll
      for (int j = 0; j < 2; ++j)
        acc[i][j] = __builtin_amdgcn_mfma_f32_16x16x32_bf16(af[i], bfr[j], acc[i][j], 0, 0, 0);
    __syncthreads();
  }

#pragma unroll
  for (int i = 0; i < 2; ++i) {
#pragma unroll
    for (int j = 0; j < 2; ++j) {
      const int colg = n0 + wn + j * 16 + md;
#pragma unroll
      for (int r = 0; r < 4; ++r) {
        const int rowg = m0 + wm + i * 16 + qd * 4 + r;
        C[(size_t)rowg * NH + colg] = acc[i][j][r] * scale;
      }
    }
  }
}

// ---------------- activation (layers 0/1): writes Zbf (bf16), G, U ----------------
__global__ __launch_bounds__(256) void k_act(
    const float* __restrict__ HP, const float* __restrict__ HPC_l,
    const float* __restrict__ bA, const float* __restrict__ bB,
    const float* __restrict__ bC,
    const float* __restrict__ anb, const float* __restrict__ anl,
    short* __restrict__ Zbf, float* __restrict__ G, float* __restrict__ U,
    int hasC)
{
  const int idx = blockIdx.x * 256 + threadIdx.x;
  const int i = idx & 1023;
  float bias = bA[i] + bB[i] + anb[i];
  if (hasC) bias += bC[i];
  const float el = expf(anl[i]);
  const float hc = HPC_l[(size_t)(idx >> 10) * (3 * NH) + i];
  const float a = (HP[idx] + hc + bias) * el;
  const float pdf = expf(-0.5f * a * a);
  const float er = erff(a * SQRT_HALF);
  Zbf[idx] = f2bf((SQRT_HPI * a * er + pdf + SQRT_HPI * a) * INV_SQRT2PI);
  G[idx] = 0.5f * (1.f + er) * el;
  U[idx] = pdf * INV_SQRT2PI * el * el;
}

// ---------------- activation (layer 2): SD2 = sqrt(t2*u2) fp32, D2g bf16 ----------------
__global__ __launch_bounds__(256) void k_act2(
    const float* __restrict__ HP, const float* __restrict__ HPC_l,
    const float* __restrict__ bA, const float* __restrict__ bB,
    const float* __restrict__ bC,
    const float* __restrict__ anb, const float* __restrict__ anl,
    const float* __restrict__ so,
    float* __restrict__ SD2, short* __restrict__ D2gbf)
{
  const int idx = blockIdx.x * 256 + threadIdx.x;
  const int i = idx & 1023;
  const float bias = bA[i] + bB[i] + bC[i] + anb[i];
  const float el = expf(anl[i]);
  const float hc = HPC_l[(size_t)(idx >> 10) * (3 * NH) + i];
  const float a = (HP[idx] + hc + bias) * el;
  const float pdf = expf(-0.5f * a * a);
  const float er = erff(a * SQRT_HALF);
  const float g = 0.5f * (1.f + er) * el;
  const float u = pdf * INV_SQRT2PI * el * el;
  const float t2 = so[i] * (1.f / NH);
  SD2[idx] = sqrtf(fmaxf(t2 * u, 0.f));
  D2gbf[idx] = f2bf(t2 * g);
}

// E1 bf16, SD1 = sqrt(t*u1) fp32
__global__ __launch_bounds__(256) void k_bw1(
    const float* __restrict__ T1, const float* __restrict__ G1,
    const float* __restrict__ U1,
    short* __restrict__ E1bf, float* __restrict__ SD1)
{
  const int idx = blockIdx.x * 256 + threadIdx.x;
  const float t = T1[idx];
  E1bf[idx] = f2bf(t * G1[idx]);
  SD1[idx] = sqrtf(fmaxf(t * U1[idx], 0.f));
}

// D0 = T0*U0 (fp32), GT0b = bf16(T0*G0)
__global__ __launch_bounds__(256) void k_bw0(
    const float* __restrict__ T0, const float* __restrict__ U0,
    const float* __restrict__ G0,
    float* __restrict__ D0, short* __restrict__ GT0b)
{
  const int idx = blockIdx.x * 256 + threadIdx.x;
  const float t = T0[idx];
  D0[idx] = t * U0[idx];
  GT0b[idx] = f2bf(t * G0[idx]);
}

// ---------------- Ah1[r,p] = bf16(G0[b,p] * Wz0[p, r&31]) ----------------
__global__ __launch_bounds__(256) void k_scale0(
    const float* __restrict__ G0, const float* __restrict__ Wz0,
    short* __restrict__ Ah1, int b0)
{
  const int idx = blockIdx.x * 256 + threadIdx.x;
  const int p = idx & 1023, r = idx >> 10;
  const int b = b0 + (r >> 5), j = r & 31;
  Ah1[idx] = f2bf(G0[(size_t)b * NH + p] * Wz0[p * NDIM + j]);
}

// ---------------- f-GEMM: MFMA partials of [NB,NH]@[NH,32] per term/k-split ----------------
__global__ __launch_bounds__(256) void k_fgemm(
    const short* __restrict__ A0, const short* __restrict__ A1,
    const short* __restrict__ A2,
    const short* __restrict__ W0T, const short* __restrict__ W1T,
    const short* __restrict__ W2T,
    float* __restrict__ partF)
{
  const int mb = blockIdx.x;          // 0..7 (128 samples)
  const int ks = blockIdx.y;          // 0..KSF-1
  const int term = blockIdx.z;        // 0..2
  const short* A  = (term == 0) ? A0 : (term == 1) ? A1 : A2;
  const short* WT = (term == 0) ? W0T : (term == 1) ? W1T : W2T;
  const int wave = threadIdx.x >> 6, lane = threadIdx.x & 63;
  const int qd = lane >> 4, md = lane & 15;
  const int m0 = mb * 128 + wave * 32;
  const int kbeg = ks * (NH / KSF);   // 128-wide slice

  float4v acc[2][2];
#pragma unroll
  for (int i = 0; i < 2; ++i)
#pragma unroll
    for (int j = 0; j < 2; ++j) acc[i][j] = (float4v)(0.f);

  for (int k0 = kbeg; k0 < kbeg + NH / KSF; k0 += 32) {
    const int kk = k0 + qd * 8;
    short8 af[2], bfr[2];
    af[0]  = *(const short8*)&A[(size_t)(m0 + md) * NH + kk];
    af[1]  = *(const short8*)&A[(size_t)(m0 + 16 + md) * NH + kk];
    bfr[0] = *(const short8*)&WT[(size_t)md * NH + kk];
    bfr[1] = *(const short8*)&WT[(size_t)(16 + md) * NH + kk];
#pragma unroll
    for (int i = 0; i < 2; ++i)
#pragma unroll
      for (int j = 0; j < 2; ++j)
        acc[i][j] = __builtin_amdgcn_mfma_f32_16x16x32_bf16(af[i], bfr[j], acc[i][j], 0, 0, 0);
  }

  float* out = &partF[(size_t)(term * KSF + ks) * NB * 32];
#pragma unroll
  for (int i = 0; i < 2; ++i)
#pragma unroll
    for (int j = 0; j < 2; ++j)
#pragma unroll
      for (int r = 0; r < 4; ++r) {
        const int row = m0 + i * 16 + qd * 4 + r;
        const int col = j * 16 + md;
        out[(size_t)row * 32 + col] = acc[i][j][r];
      }
}

// ---------------- reduce f partials + epilogue ----------------
__global__ __launch_bounds__(256) void k_fred(
    const float* __restrict__ partF, const float* __restrict__ X,
    const float* __restrict__ Wxout,
    const float* __restrict__ w0p, const float* __restrict__ w1p,
    float* __restrict__ outF)
{
  const int e = blockIdx.x * 256 + threadIdx.x;   // 0 .. NB*32-1
  float s = 0.f;
#pragma unroll
  for (int p = 0; p < 3 * KSF; ++p) s += partF[(size_t)p * NB * 32 + e];
  const float spw0 = sp_f(w0p[0]);
  const float spw1 = sp_f(w1p[0]);
  outF[e] = spw1 * (s + Wxout[e & 31]) + spw0 * X[e];
}

// ---------------- K-split per-sample Gram partials (no LDS, no barriers) ----------------
__global__ __launch_bounds__(256) void k_gram(
    const short* __restrict__ Q1, const short* __restrict__ Q2,
    const short* __restrict__ W0T, const float* __restrict__ D0,
    float* __restrict__ partH, int b0)
{
  const int ns = blockIdx.x, bl = blockIdx.y;
  const int b = b0 + bl;
  const int wave = threadIdx.x >> 6, lane = threadIdx.x & 63;
  const int wm = (wave >> 1) << 4, wn = (wave & 1) << 4;
  const int qd = lane >> 4, md = lane & 15;
  const int kbeg = ns << 7;           // ns * 128
  const size_t rb = (size_t)bl * 32 * NH;

  float4v acc = (float4v)(0.f);

  // layer 0: Gram0 = W0^T diag(D0) W0  (scale A-side by D0 in registers)
  for (int k0 = kbeg; k0 < kbeg + 128; k0 += 32) {
    const int kk = k0 + qd * 8;
    const short8 ar = *(const short8*)&W0T[(size_t)(wm + md) * NH + kk];
    float dd[8];
    *(float4*)&dd[0] = *(const float4*)&D0[(size_t)b * NH + kk];
    *(float4*)&dd[4] = *(const float4*)&D0[(size_t)b * NH + kk + 4];
    short8 af;
#pragma unroll
    for (int e = 0; e < 8; ++e) af[e] = f2bf(bf2f(ar[e]) * dd[e]);
    const short8 bfr = *(const short8*)&W0T[(size_t)(wn + md) * NH + kk];
    acc = __builtin_amdgcn_mfma_f32_16x16x32_bf16(af, bfr, acc, 0, 0, 0);
  }
  // layers 1,2: Gram = Q Q^T (Q pre-scaled by sqrt(D))
#pragma unroll
  for (int l = 0; l < 2; ++l) {
    const short* Q = (l == 0) ? Q1 : Q2;
    for (int k0 = kbeg; k0 < kbeg + 128; k0 += 32) {
      const int kk = k0 + qd * 8;
      const short8 af  = *(const short8*)&Q[rb + (size_t)(wm + md) * NH + kk];
      const short8 bfr = *(const short8*)&Q[rb + (size_t)(wn + md) * NH + kk];
      acc = __builtin_amdgcn_mfma_f32_16x16x32_bf16(af, bfr, acc, 0, 0, 0);
    }
  }

  float* out = &partH[((size_t)bl * NS + ns) * 1024];
#pragma unroll
  for (int r = 0; r < 4; ++r)
    out[(wm + qd * 4 + r) * 32 + (wn + md)] = acc[r];
}

// ---------------- reduce partials + Cholesky logdet ----------------
__global__ __launch_bounds__(256) void k_gram2(
    const float* __restrict__ partH,
    const float* __restrict__ w0p, const float* __restrict__ w1p,
    float* __restrict__ outLD, int b0)
{
  const int bl = blockIdx.x, b = b0 + bl, tid = threadIdx.x;
  __shared__ float sH[32][33];
  __shared__ float sred[32];
  const float spw0 = sp_f(w0p[0]);
  const float spw1 = sp_f(w1p[0]);
  const float* base = &partH[(size_t)bl * NS * 1024];
#pragma unroll
  for (int r = 0; r < 4; ++r) {
    const int e = r * 256 + tid;
    float s = 0.f;
#pragma unroll
    for (int ns = 0; ns < NS; ++ns) s += base[ns * 1024 + e];
    float h = s * spw1;
    const int row = e >> 5, col = e & 31;
    if (row == col) h += spw0;
    sH[row][col] = h;
  }
  __syncthreads();

  float ldacc = 0.f;
  for (int c = 0; c < 32; ++c) {
    if (tid >= c && tid < 32) {
      float s = sH[tid][c];
      for (int m = 0; m < c; ++m) s -= sH[tid][m] * sH[c][m];
      sred[tid] = s;
    }
    __syncthreads();
    const float sc = sred[c];
    if (tid >= c && tid < 32) {
      const float lcc = sqrtf(sc);
      sH[tid][c] = (tid == c) ? lcc : sred[tid] / lcc;
    }
    ldacc += logf(sc);
    __syncthreads();
  }
  if (tid == 0) outLD[b] = ldacc;
}

// ---------------- launcher ----------------
extern "C" void kernel_launch(void* const* d_in, const int* in_sizes, int n_in,
                              void* d_out, int out_size, void* d_ws, size_t ws_size,
                              hipStream_t stream)
{
  const float* X    = (const float*)d_in[0];
  const float* Cc   = (const float*)d_in[1];
  const float* w0   = (const float*)d_in[2];
  const float* w1   = (const float*)d_in[3];
  const float* Wz0w = (const float*)d_in[4];
  const float* Wz0b = (const float*)d_in[5];
  const float* Wc0w = (const float*)d_in[6];
  const float* Wc0b = (const float*)d_in[7];
  const float* an0b = (const float*)d_in[8];
  const float* an0l = (const float*)d_in[9];
  const float* Wz1w = (const float*)d_in[10];
  const float* Wz1b = (const float*)d_in[11];
  const float* Wx1w = (const float*)d_in[12];
  const float* Wx1b = (const float*)d_in[13];
  const float* Wc1w = (const float*)d_in[14];
  const float* Wc1b = (const float*)d_in[15];
  const float* an1b = (const float*)d_in[16];
  const float* an1l = (const float*)d_in[17];
  const float* Wz2w = (const float*)d_in[18];
  const float* Wz2b = (const float*)d_in[19];
  const float* Wx2w = (const float*)d_in[20];
  const float* Wx2b = (const float*)d_in[21];
  const float* Wc2w = (const float*)d_in[22];
  const float* Wc2b = (const float*)d_in[23];
  const float* an2b = (const float*)d_in[24];
  const float* an2l = (const float*)d_in[25];
  const float* Wzoutw = (const float*)d_in[26];
  const float* Wxoutw = (const float*)d_in[27];
  // d_in[28] (Wcout_w): constant in x -> no grad/Hessian contribution.

  float* ws = (float*)d_ws;
  size_t off = 0;
  auto alloc = [&](size_t n) {
    float* p = ws + off; off += (n + 3) & ~(size_t)3; return p;
  };
  const size_t HH = (size_t)NH * NH;
  const size_t BH = (size_t)NB * NH;

  short* S1b  = (short*)alloc(HH / 2);
  short* S2b  = (short*)alloc(HH / 2);
  short* S1Tb = (short*)alloc(HH / 2);
  short* S2Tb = (short*)alloc(HH / 2);
  // NOTE: Wc0bb/Wc1bb/Wc2bb must stay contiguous (fused c-GEMM Bt = concat)
  short* Wc0bb = (short*)alloc((size_t)NH * NC / 2);
  short* Wc1bb = (short*)alloc((size_t)NH * NC / 2);
  short* Wc2bb = (short*)alloc((size_t)NH * NC / 2);
  short* Ccb  = (short*)alloc((size_t)NB * NC / 2);
  short* W0Tb = (short*)alloc((size_t)NDIM * NH / 2);
  short* Wx1Tb = (short*)alloc((size_t)NDIM * NH / 2);
  short* Wx2Tb = (short*)alloc((size_t)NDIM * NH / 2);
  float* so   = alloc(NH);
  float* HP   = alloc(BH);
  float* HPC  = alloc((size_t)NB * 3 * NH);   // fused c-path output [NB, 3*NH]
  short* Z0b  = (short*)alloc(BH / 2);
  short* Z1b  = (short*)alloc(BH / 2);
  float* G0   = alloc(BH);
  float* U0   = alloc(BH);
  float* G1   = alloc(BH);
  float* U1   = alloc(BH);
  float* SD2  = alloc(BH);
  short* D2gb = (short*)alloc(BH / 2);
  float* T1   = alloc(BH);
  short* E1b  = (short*)alloc(BH / 2);
  float* SD1  = alloc(BH);
  float* T0   = alloc(BH);
  float* D0   = alloc(BH);
  short* GT0b = (short*)alloc(BH / 2);
  float* partF = alloc((size_t)3 * KSF * NB * 32);

  // chunk buffers: Ah1, A2, Q1, Q2 (bf16) + partH (fp32)
  const size_t avail_f = ws_size / sizeof(float);
  int CB = 32;
  const int cands[6] = {1024, 512, 256, 128, 64, 32};
  for (int ci = 0; ci < 6; ++ci) {
    const size_t need = off + 4 * ((size_t)cands[ci] * 32 * NH / 2 + 4)
                      + (size_t)cands[ci] * NS * 1024 + 64;
    if (need <= avail_f) { CB = cands[ci]; break; }
  }
  const size_t chunk_sh = (size_t)CB * 32 * NH;   // shorts per bf16 buffer
  short* Ah1 = (short*)alloc(chunk_sh / 2);
  short* A2b = (short*)alloc(chunk_sh / 2);
  short* Q1b = (short*)alloc(chunk_sh / 2);
  short* Q2b = (short*)alloc(chunk_sh / 2);
  float* partH = alloc((size_t)CB * NS * 1024);

  float* outF  = (float*)d_out;
  float* outLD = (float*)d_out + NB * NDIM;

  const dim3 blk2(16, 16);
  const dim3 gridX(16, NB / 64);            // fp32 gemm, K=32 terms
  const dim3 gridE(NB * NH / 256);
  const dim3 grid64(NB / 64, NH / 64);      // 64-tile mfma (x = M-block, XCD swizzle)
  const dim3 gridC(NB / 128, 3 * NH / 128); // fused c-GEMM (x = M-block)
  const float invH = 1.0f / (float)NH;

  k_prep<<<dim3(HH / 256), dim3(256), 0, stream>>>(
      Wz1w, Wz2w, Wzoutw, Wz0w, Wx1w, Wx2w, Wc0w, Wc1w, Wc2w, Cc,
      S1b, S1Tb, S2b, S2Tb, Wc0bb, Wc1bb, Wc2bb, Ccb, W0Tb, Wx1Tb, Wx2Tb, so);

  // fused c-path: HPC[s, l*NH + i] = (Cc @ Wc_l^T)[s, i], one 128-tile GEMM
  k_m128<<<gridC, dim3(256), 0, stream>>>(Ccb, Wc0bb, HPC, 1.f, NC, 3 * NH);

  // layer 0: a0 = X@Wz0^T + HPC0 (+ biases in k_act)
  k_gemm<0><<<gridX, blk2, 0, stream>>>(X, Wz0w, HP, NDIM, NDIM, 1.f);
  k_act<<<gridE, dim3(256), 0, stream>>>(HP, HPC + 0 * NH, Wz0b, Wc0b, nullptr,
                                         an0b, an0l, Z0b, G0, U0, 0);
  // layer 1
  k_mgemm64<<<grid64, dim3(256), 0, stream>>>(Z0b, S1b, HP, invH, NH);
  k_gemm<1><<<gridX, blk2, 0, stream>>>(X, Wx1w, HP, NDIM, NDIM, 1.f);
  k_act<<<gridE, dim3(256), 0, stream>>>(HP, HPC + 1 * NH, Wz1b, Wx1b, Wc1b,
                                         an1b, an1l, Z1b, G1, U1, 1);
  // layer 2
  k_mgemm64<<<grid64, dim3(256), 0, stream>>>(Z1b, S2b, HP, invH, NH);
  k_gemm<1><<<gridX, blk2, 0, stream>>>(X, Wx2w, HP, NDIM, NDIM, 1.f);
  k_act2<<<gridE, dim3(256), 0, stream>>>(HP, HPC + 2 * NH, Wz2b, Wx2b, Wc2b,
                                          an2b, an2l, so, SD2, D2gb);
  // backward sensitivities
  k_mgemm64<<<grid64, dim3(256), 0, stream>>>(D2gb, S2Tb, T1, invH, NH);
  k_bw1<<<gridE, dim3(256), 0, stream>>>(T1, G1, U1, E1b, SD1);
  k_mgemm64<<<grid64, dim3(256), 0, stream>>>(E1b, S1Tb, T0, invH, NH);
  k_bw0<<<gridE, dim3(256), 0, stream>>>(T0, U0, G0, D0, GT0b);

  // f (grad) via MFMA partials + reduce
  k_fgemm<<<dim3(8, KSF, 3), dim3(256), 0, stream>>>(
      GT0b, E1b, D2gb, W0Tb, Wx1Tb, Wx2Tb, partF);
  k_fred<<<dim3(NB * 32 / 256), dim3(256), 0, stream>>>(
      partF, X, Wxoutw, w0, w1, outF);

  // Jacobian propagation + K-split Gram + Cholesky, chunked over samples
  const dim3 gridJ(CB * 32 / 128, NH / 128);   // x = M-block (XCD swizzle)
  const dim3 gridS((size_t)CB * 32 * NH / 256);
  const dim3 gridG(NS, CB);
  for (int b0 = 0; b0 < NB; b0 += CB) {
    k_scale0<<<gridS, dim3(256), 0, stream>>>(G0, Wz0w, Ah1, b0);
    k_mgemm<2><<<gridJ, dim3(256), 0, stream>>>(Ah1, S1b, Q1b, A2b,
                                                G1, SD1, Wx1w, invH, NH, b0);
    k_mgemm<1><<<gridJ, dim3(256), 0, stream>>>(A2b, S2b, Q2b, nullptr,
                                                nullptr, SD2, Wx2w, invH, NH, b0);
    k_gram<<<gridG, dim3(256), 0, stream>>>(Q1b, Q2b, W0Tb, D0, partH, b0);
    k_gram2<<<dim3(CB), dim3(256), 0, stream>>>(partH, w0, w1, outLD, b0);
  }
}